// Round 1
// 719.813 us; speedup vs baseline: 1.3517x; 1.3517x over previous
//
#include <hip/hip_runtime.h>
#include <hip/hip_bf16.h>

typedef __hip_bfloat16 bf16;
typedef __attribute__((ext_vector_type(8))) short bf16x8;
typedef __attribute__((ext_vector_type(4))) float f32x4;
typedef __attribute__((ext_vector_type(4))) unsigned short us4;

// Problem constants
#define NB   256           // batch
#define NN   23            // nodes
#define NL   35            // seq len
#define NNL  805           // NN*NL
#define CNL  51520         // NC*NNL (per-batch x elements)
#define NSQ  529           // NN*NN
#define HF   1587          // NH*NSQ
#define NCN  1472          // 64*23 (one X_l slice)

// ws layout (float offsets)
#define OFF_W     0         // [3][64][64]
#define OFF_U1    12288
#define OFF_U2    12480
#define OFF_S     12672
#define OFF_ATTM  12800     // [256][1587]
#define OFF_MEAN  419072
#define OFF_RSTD  420672
#define OFF_A     422272    // [256][1587] -> 828544
#define OFF_MWT   828544    // mwT [3][64c][64o] -> 840832
#define OFF_MBS   840832    // mbsum[64] -> pad 840960
#define OFF_XT    840960    // xt fp32 [256][35][1472] = 13,189,120 -> 14,030,080
#define OFF_Y     14030080  // bf16 ybuf per pass [128][23][35][64] = 13.2 MB
// total ~69.3 MB

// split-bf16 helpers: x = hi + lo, each exactly representable in bf16
__device__ inline unsigned short bfh(float x) {
    unsigned u = __float_as_uint(x);
    return (unsigned short)((u + 0x7FFFu + ((u >> 16) & 1u)) >> 16);  // RNE
}
__device__ inline float bfh2f(unsigned short h) {
    return __uint_as_float(((unsigned)h) << 16);
}

// ---------------------------------------------------------------------------
// Kernel 0: transpose x[b][c][n][l] -> xt[b][l][c*23+n], fp32. Block per b.
__global__ __launch_bounds__(1024) void k_xt(const float* __restrict__ x,
                                             float* __restrict__ ws) {
    int b = blockIdx.x, t = threadIdx.x;
    __shared__ float sx[32 * 805];       // 103 KB: half the channels at a time
    const float* xb = x + b * CNL;
    float* xtb = ws + OFF_XT + b * CNL;  // [l][c*23+n]
    for (int ch = 0; ch < 2; ch++) {
        if (ch) __syncthreads();
        for (int i = t; i < 25760; i += 1024) sx[i] = xb[ch * 25760 + i];
        __syncthreads();
        // write: idx = l*736 + r, r = cc*23+n ; src sx[cc*805 + n*35 + l]
        for (int idx = t; idx < 25760; idx += 1024) {
            int l = idx / 736, r = idx - l * 736;
            int cc = r / 23, n = r - cc * 23;
            xtb[l * NCN + ch * 736 + r] = sx[cc * 805 + n * 35 + l];
        }
    }
}

// ---------------------------------------------------------------------------
// Kernel 1: fold projection weights; block 3 transposes mw and sums mb.
__global__ __launch_bounds__(256) void k_prep(const float* __restrict__ cw1,
                                              const float* __restrict__ cb1,
                                              const float* __restrict__ cw2,
                                              const float* __restrict__ cb2,
                                              const float* __restrict__ mw,
                                              const float* __restrict__ mb,
                                              float* __restrict__ ws) {
    int h = blockIdx.x, t = threadIdx.x;
    __shared__ float s1[4096], s2[4096];
    if (h < 3) {
        for (int i = t; i < 4096; i += 256) {
            s1[i] = cw1[h * 4096 + i];
            s2[i] = cw2[h * 4096 + i];
        }
        __syncthreads();
        for (int i = t; i < 4096; i += 256) {
            int c2 = i >> 6, c1 = i & 63;
            float acc = 0.f;
            for (int o = 0; o < 64; o++) acc += s2[o * 64 + c2] * s1[o * 64 + c1];
            ws[OFF_W + h * 4096 + i] = acc;
        }
        if (t < 64) {
            float a = 0.f, b2 = 0.f;
            for (int o = 0; o < 64; o++) {
                a  += cb2[h * 64 + o] * s1[o * 64 + t];
                b2 += cb1[h * 64 + o] * s2[o * 64 + t];
            }
            ws[OFF_U1 + h * 64 + t] = a;
            ws[OFF_U2 + h * 64 + t] = b2;
        }
        if (t == 0) {
            float a = 0.f;
            for (int o = 0; o < 64; o++) a += cb1[h * 64 + o] * cb2[h * 64 + o];
            ws[OFF_S + h] = a;
        }
    } else {
        for (int i = t; i < 12288; i += 256) {
            int hh = i >> 12, rem = i & 4095, o = rem >> 6, c = rem & 63;
            ws[OFF_MWT + (hh * 64 + c) * 64 + o] = mw[i];
        }
        if (t < 64) ws[OFF_MBS + t] = mb[t] + mb[64 + t] + mb[128 + t];
    }
}

// ---------------------------------------------------------------------------
// Kernel 2 (MFMA rewrite): att_m[b,h,m,n] =
//   (sum_l X_l^T W X_l + a1[n] + a2[m] + 35*s) / 2240
// Split-bf16 (hi+lo, 3 MFMAs per product) for fp32-level accuracy.
// Per (b,h) block, 4 waves:
//   phase A: P_l(64x32) = W(64x64) @ X_l(64x32); wave w owns rows 16w..16w+15
//   phase B: att(32x32) += X_l^T @ P_l; wave w owns tile (mt,nt)=(w>>1,w&1)
// X_l staged transposed [n][c] bf16 hi/lo, row stride 72 (16B-aligned rows).
// att accumulator lives in MFMA C-regs across all 35 l.
__global__ __launch_bounds__(256) void k_attm(float* __restrict__ ws) {
    const int b = blockIdx.x, h = blockIdx.y, t = threadIdx.x;
    const int lane = t & 63;
    const int w = __builtin_amdgcn_readfirstlane(t >> 6);   // wave 0..3
    const int lg = lane >> 4;      // k-group 0..3
    const int lr = lane & 15;      // row/col within 16-tile

    __shared__ unsigned short sXh[2][32 * 72];   // X^T hi, double-buffered
    __shared__ unsigned short sXl[2][32 * 72];   // X^T lo
    __shared__ unsigned short sPh[32 * 72];      // P^T hi  [n][c2]
    __shared__ unsigned short sPl[32 * 72];      // P^T lo
    __shared__ float sxs[64 * 25];               // sum_l X  [c][n], stride 25
    __shared__ float sA1[23], sA2[23];

    const float* xtb = ws + OFF_XT + (size_t)b * CNL;

    // --- W fragments (phase-A A-operand), hoisted: rows 16w+lr, split hi/lo ---
    bf16x8 wh[2], wl[2];
    {
        const float* Wg = ws + OFF_W + h * 4096 + (16 * w + lr) * 64;
        #pragma unroll
        for (int s = 0; s < 2; s++) {
            const float* p = Wg + 32 * s + 8 * lg;
            float4 v0 = *(const float4*)(p);
            float4 v1 = *(const float4*)(p + 4);
            float vv[8] = {v0.x, v0.y, v0.z, v0.w, v1.x, v1.y, v1.z, v1.w};
            #pragma unroll
            for (int e = 0; e < 8; e++) {
                unsigned short hb = bfh(vv[e]);
                wh[s][e] = (short)hb;
                wl[s][e] = (short)bfh(vv[e] - bfh2f(hb));
            }
        }
    }

    const int mt = w >> 1, nt = w & 1;           // phase-B tile
    f32x4 attC = {0.f, 0.f, 0.f, 0.f};
    float xs[6] = {0.f, 0.f, 0.f, 0.f, 0.f, 0.f};

    #pragma unroll 1
    for (int l = 0; l < NL; l++) {
        const int cur = l & 1;
        // --- stage X_l: coalesced fp32 read, split hi/lo, transpose to [n][c] ---
        {
            const float* src = xtb + (size_t)l * NCN;
            unsigned short* xh = sXh[cur];
            unsigned short* xl = sXl[cur];
            #pragma unroll
            for (int j = 0; j < 6; j++) {
                int i = t + 256 * j;
                if (i < NCN) {
                    float v = src[i];
                    xs[j] += v;
                    int n = i % 23, c = i / 23;
                    unsigned short hb = bfh(v);
                    xh[n * 72 + c] = hb;
                    xl[n * 72 + c] = bfh(v - bfh2f(hb));
                }
            }
        }
        __syncthreads();   // X ready; prev-iter P consumers also done

        const unsigned short* xh = sXh[cur];
        const unsigned short* xl = sXl[cur];

        // --- phase A: P rows [16w,16w+16) x n-tiles {0,1}, K = 64 ---
        f32x4 pc[2];
        #pragma unroll
        for (int ntt = 0; ntt < 2; ntt++) {
            f32x4 c = {0.f, 0.f, 0.f, 0.f};
            #pragma unroll
            for (int s = 0; s < 2; s++) {
                int off = (ntt * 16 + lr) * 72 + 32 * s + 8 * lg;
                bf16x8 bh = *(const bf16x8*)(xh + off);
                bf16x8 bl = *(const bf16x8*)(xl + off);
                c = __builtin_amdgcn_mfma_f32_16x16x32_bf16(wh[s], bh, c, 0, 0, 0);
                c = __builtin_amdgcn_mfma_f32_16x16x32_bf16(wh[s], bl, c, 0, 0, 0);
                c = __builtin_amdgcn_mfma_f32_16x16x32_bf16(wl[s], bh, c, 0, 0, 0);
            }
            pc[ntt] = c;
        }
        // write P^T[n][c2] hi/lo; C-frag row = 4*lg+reg -> 4 consecutive c2
        #pragma unroll
        for (int ntt = 0; ntt < 2; ntt++) {
            int n = ntt * 16 + lr;
            int c2 = 16 * w + 4 * lg;
            us4 ph4, pl4;
            #pragma unroll
            for (int r = 0; r < 4; r++) {
                float v = pc[ntt][r];
                unsigned short hb = bfh(v);
                ph4[r] = hb;
                pl4[r] = bfh(v - bfh2f(hb));
            }
            *(us4*)(sPh + n * 72 + c2) = ph4;
            *(us4*)(sPl + n * 72 + c2) = pl4;
        }
        __syncthreads();   // P ready

        // --- phase B: att(mt,nt) += X^T @ P, K = 64 ---
        #pragma unroll
        for (int s = 0; s < 2; s++) {
            int aoff = (mt * 16 + lr) * 72 + 32 * s + 8 * lg;
            int boff = (nt * 16 + lr) * 72 + 32 * s + 8 * lg;
            bf16x8 ah = *(const bf16x8*)(xh + aoff);
            bf16x8 al = *(const bf16x8*)(xl + aoff);
            bf16x8 bh = *(const bf16x8*)(sPh + boff);
            bf16x8 bl = *(const bf16x8*)(sPl + boff);
            attC = __builtin_amdgcn_mfma_f32_16x16x32_bf16(ah, bh, attC, 0, 0, 0);
            attC = __builtin_amdgcn_mfma_f32_16x16x32_bf16(ah, bl, attC, 0, 0, 0);
            attC = __builtin_amdgcn_mfma_f32_16x16x32_bf16(al, bh, attC, 0, 0, 0);
        }
        // no trailing barrier: next stage writes the other X buffer; next
        // phase-A P writes are fenced by the next stage barrier.
    }

    // --- rank-1 correction terms from exact fp32 column sums ---
    #pragma unroll
    for (int j = 0; j < 6; j++) {
        int i = t + 256 * j;
        if (i < NCN) sxs[(i / 23) * 25 + (i % 23)] = xs[j];
    }
    __syncthreads();
    if (t < 23) {
        float a = 0.f;
        const float* u = ws + OFF_U1 + h * 64;
        for (int c = 0; c < 64; c++) a += u[c] * sxs[c * 25 + t];
        sA1[t] = a;
    } else if (t >= 32 && t < 55) {
        int n = t - 32;
        float a = 0.f;
        const float* u = ws + OFF_U2 + h * 64;
        for (int c = 0; c < 64; c++) a += u[c] * sxs[c * 25 + n];
        sA2[n] = a;
    }
    __syncthreads();

    float sh = ws[OFF_S + h];
    float* o = ws + OFF_ATTM + (size_t)b * HF + h * NSQ;
    int n = nt * 16 + lr;
    if (n < 23) {
        #pragma unroll
        for (int r = 0; r < 4; r++) {
            int m = mt * 16 + 4 * lg + r;
            if (m < 23)
                o[m * 23 + n] = (attC[r] + sA1[n] + sA2[m] + 35.f * sh) * (1.f / 2240.f);
        }
    }
}

// ---------------------------------------------------------------------------
// Kernel 3: BN batch statistics per (h, feature).
__global__ __launch_bounds__(256) void k_bn(float* __restrict__ ws) {
    int f = blockIdx.x * 256 + threadIdx.x;
    if (f >= HF) return;
    const float* p = ws + OFF_ATTM + f;
    float s = 0.f, s2 = 0.f;
    for (int b = 0; b < NB; b++) {
        float v = p[b * HF];
        s += v; s2 += v * v;
    }
    float mean = s * (1.f / 256.f);
    float var  = s2 * (1.f / 256.f) - mean * mean;
    ws[OFF_MEAN + f] = mean;
    ws[OFF_RSTD + f] = rsqrtf(var + 1e-5f);
}

// ---------------------------------------------------------------------------
// Kernel 4: normalize, softmax over rows, A = A_ske + att + A_adp.
__global__ __launch_bounds__(256) void k_adp(const float* __restrict__ gamma,
                                             const float* __restrict__ beta,
                                             const float* __restrict__ att,
                                             const float* __restrict__ aske,
                                             float* __restrict__ ws) {
    int b = blockIdx.x, h = blockIdx.y, t = threadIdx.x;
    __shared__ float sv[529];
    const float* am   = ws + OFF_ATTM + b * HF + h * NSQ;
    const float* mean = ws + OFF_MEAN + h * NSQ;
    const float* rstd = ws + OFF_RSTD + h * NSQ;
    for (int i = t; i < 529; i += 256) {
        sv[i] = (am[i] - mean[i]) * rstd[i] * gamma[h * NSQ + i] + beta[h * NSQ + i];
    }
    __syncthreads();
    if (t < 23) {
        float mx = -1e30f;
        #pragma unroll
        for (int m = 0; m < 23; m++) mx = fmaxf(mx, sv[m * 23 + t]);
        float e[23];
        float sum = 0.f;
        #pragma unroll
        for (int m = 0; m < 23; m++) {
            float v = __expf(sv[m * 23 + t] - mx);
            e[m] = v; sum += v;
        }
        float inv = 1.f / sum;
        #pragma unroll
        for (int m = 0; m < 23; m++) sv[m * 23 + t] = e[m] * inv;
    }
    __syncthreads();
    float* o = ws + OFF_A + b * HF + h * NSQ;
    for (int i = t; i < 529; i += 256) {
        o[i] = sv[i] + aske[h * NSQ + i] + att[h * NSQ + i];
    }
}

// ---------------------------------------------------------------------------
// Kernel 5: graph conv, lane = o. Wave = one (b,l). x rows are contiguous in
// xt -> uniform s_load_dwordx8 merges. h-loop ROLLED (forced) with per-h
// mwreg[64] fully unrolled so it stays register-resident (R3 lesson).
__global__ __launch_bounds__(256) void k_gcn(const float* __restrict__ ws,
                                             bf16* __restrict__ ybuf,
                                             int pass) {
    const int l  = blockIdx.x;          // 0..34
    const int by = blockIdx.y;          // 0..31
    const int lane = threadIdx.x & 63;  // = o
    const int w = __builtin_amdgcn_readfirstlane((int)(threadIdx.x >> 6));
    const int bb = by * 4 + w;          // 0..127 within pass
    const int b  = pass * 128 + bb;

    const float* xrow0 = ws + OFF_XT + ((size_t)b * NL + l) * NCN;
    const float* Ab    = ws + OFF_A + b * HF;
    const float* mwt   = ws + OFF_MWT;

    float y[23];
    float mbs = ws[OFF_MBS + lane];
    #pragma unroll
    for (int m = 0; m < 23; m++) y[m] = mbs;

    #pragma unroll 1
    for (int h = 0; h < 3; h++) {
        float mwreg[64];
        #pragma unroll
        for (int c = 0; c < 64; c++) mwreg[c] = mwt[(h * 64 + c) * 64 + lane];
        float z[23];
        #pragma unroll
        for (int n = 0; n < 23; n++) z[n] = 0.f;
        #pragma unroll
        for (int c = 0; c < 64; c++) {
            const float* xr = xrow0 + c * 23;   // uniform -> scalar loads
            #pragma unroll
            for (int n = 0; n < 23; n++) z[n] += mwreg[c] * xr[n];
        }
        const float* Ah = Ab + h * NSQ;
        #pragma unroll
        for (int n = 0; n < 23; n++) {
            float zn = z[n];
            #pragma unroll
            for (int m = 0; m < 23; m++) y[m] += Ah[n * 23 + m] * zn;
        }
    }
    bf16* yp = ybuf + ((size_t)(bb * NN) * NL + l) * 64 + lane;
    #pragma unroll
    for (int m = 0; m < 23; m++)
        yp[(size_t)m * (NL * 64)] = __float2bfloat16(y[m]);
}

// ---------------------------------------------------------------------------
// Kernel 6: temporal FC. out[b,o,m,lp] = sum_l y[b,m,l,o]*W[l,lp] + bias[lp]
__global__ __launch_bounds__(512, 2) void k_fc(const float* __restrict__ wseq,
                                               const float* __restrict__ bias,
                                               const bf16* __restrict__ ybuf,
                                               float* __restrict__ out,
                                               int pass) {
    const int bb = blockIdx.x;
    const int b  = pass * 128 + bb;
    const int o  = threadIdx.x & 63;
    const int mg = __builtin_amdgcn_readfirstlane((int)(threadIdx.x >> 6)); // 0..7

    float acc[3][35];
    #pragma unroll
    for (int r = 0; r < 3; r++)
        #pragma unroll
        for (int lp = 0; lp < 35; lp++) acc[r][lp] = bias[lp];

    const bf16* yb = ybuf + o;
    for (int l = 0; l < NL; l++) {
        float y0 = __bfloat162float(yb[((size_t)(bb * NN + mg) * NL + l) * 64]);
        float y1 = __bfloat162float(yb[((size_t)(bb * NN + mg + 8) * NL + l) * 64]);
        float y2 = (mg < 7) ? __bfloat162float(yb[((size_t)(bb * NN + mg + 16) * NL + l) * 64]) : 0.f;
        const float* wr = wseq + l * 35;
        #pragma unroll
        for (int lp = 0; lp < 35; lp++) {
            float wv = wr[lp];
            acc[0][lp] += y0 * wv;
            acc[1][lp] += y1 * wv;
            acc[2][lp] += y2 * wv;
        }
    }
    #pragma unroll
    for (int r = 0; r < 3; r++) {
        int m = mg + 8 * r;
        if (m < 23) {
            float* op = out + ((size_t)(b * 64 + o) * 23 + m) * 35;
            #pragma unroll
            for (int lp = 0; lp < 35; lp++) op[lp] = acc[r][lp];
        }
    }
}

// ---------------------------------------------------------------------------
extern "C" void kernel_launch(void* const* d_in, const int* in_sizes, int n_in,
                              void* d_out, int out_size, void* d_ws, size_t ws_size,
                              hipStream_t stream) {
    const float* x    = (const float*)d_in[0];
    const float* cw1  = (const float*)d_in[1];
    const float* cb1  = (const float*)d_in[2];
    const float* cw2  = (const float*)d_in[3];
    const float* cb2  = (const float*)d_in[4];
    const float* gam  = (const float*)d_in[5];
    const float* bet  = (const float*)d_in[6];
    const float* mw   = (const float*)d_in[7];
    const float* mb   = (const float*)d_in[8];
    const float* att  = (const float*)d_in[9];
    const float* aske = (const float*)d_in[10];
    const float* wsq  = (const float*)d_in[11];
    const float* bias = (const float*)d_in[12];
    float* ws = (float*)d_ws;
    bf16* ybuf = (bf16*)(ws + OFF_Y);
    float* out = (float*)d_out;

    hipLaunchKernelGGL(k_prep, dim3(4),       dim3(256),  0, stream, cw1, cb1, cw2, cb2, mw, mb, ws);
    hipLaunchKernelGGL(k_xt,   dim3(256),     dim3(1024), 0, stream, x, ws);
    hipLaunchKernelGGL(k_attm, dim3(256, 3),  dim3(256),  0, stream, ws);
    hipLaunchKernelGGL(k_bn,   dim3(7),       dim3(256),  0, stream, ws);
    hipLaunchKernelGGL(k_adp,  dim3(256, 3),  dim3(256),  0, stream, gam, bet, att, aske, ws);
    hipLaunchKernelGGL(k_gcn,  dim3(35, 32),  dim3(256),  0, stream, ws, ybuf, 0);
    hipLaunchKernelGGL(k_fc,   dim3(128),     dim3(512),  0, stream, wsq, bias, ybuf, out, 0);
    hipLaunchKernelGGL(k_gcn,  dim3(35, 32),  dim3(256),  0, stream, ws, ybuf, 1);
    hipLaunchKernelGGL(k_fc,   dim3(128),     dim3(512),  0, stream, wsq, bias, ybuf, out, 1);
}

// Round 3
// 322.799 us; speedup vs baseline: 3.0141x; 2.2299x over previous
//
#include <hip/hip_runtime.h>
#include <hip/hip_bf16.h>

typedef __hip_bfloat16 bf16;
typedef __attribute__((ext_vector_type(8))) short bf16x8;
typedef __attribute__((ext_vector_type(4))) float f32x4;
typedef __attribute__((ext_vector_type(4))) unsigned short us4;

// Problem constants
#define NB   256           // batch
#define NN   23            // nodes
#define NL   35            // seq len
#define NNL  805           // NN*NL
#define CNL  51520         // NC*NNL (per-batch x elements)
#define NSQ  529           // NN*NN
#define HF   1587          // NH*NSQ
#define NCN  1472          // 64*23 (one X_l slice)

// ws layout (float offsets)
#define OFF_W     0         // [3][64][64]
#define OFF_U1    12288
#define OFF_U2    12480
#define OFF_S     12672
#define OFF_ATTM  12800     // [256][1587]
#define OFF_MEAN  419072
#define OFF_RSTD  420672
#define OFF_A     422272    // [256][1587] -> 828544
#define OFF_MWH   828544    // mw bf16 hi [3][64o][64c] (12288 shorts = 6144 floats)
#define OFF_MWL   834688    // mw bf16 lo
#define OFF_MBS   840832    // mbsum[64] -> pad 840960
#define OFF_XT    840960    // xt fp32 [256][35][1472] = 13,189,120 -> 14,030,080

// split-bf16 helpers: x = hi + lo, each exactly representable in bf16
__device__ inline unsigned short bfh(float x) {
    unsigned u = __float_as_uint(x);
    return (unsigned short)((u + 0x7FFFu + ((u >> 16) & 1u)) >> 16);  // RNE
}
__device__ inline float bfh2f(unsigned short h) {
    return __uint_as_float(((unsigned)h) << 16);
}

// ---------------------------------------------------------------------------
// Kernel 0: transpose x[b][c][n][l] -> xt[b][l][c*23+n], fp32. Block per b.
__global__ __launch_bounds__(1024) void k_xt(const float* __restrict__ x,
                                             float* __restrict__ ws) {
    int b = blockIdx.x, t = threadIdx.x;
    __shared__ float sx[32 * 805];       // 103 KB: half the channels at a time
    const float* xb = x + b * CNL;
    float* xtb = ws + OFF_XT + b * CNL;  // [l][c*23+n]
    for (int ch = 0; ch < 2; ch++) {
        if (ch) __syncthreads();
        for (int i = t; i < 25760; i += 1024) sx[i] = xb[ch * 25760 + i];
        __syncthreads();
        // write: idx = l*736 + r, r = cc*23+n ; src sx[cc*805 + n*35 + l]
        for (int idx = t; idx < 25760; idx += 1024) {
            int l = idx / 736, r = idx - l * 736;
            int cc = r / 23, n = r - cc * 23;
            xtb[l * NCN + ch * 736 + r] = sx[cc * 805 + n * 35 + l];
        }
    }
}

// ---------------------------------------------------------------------------
// Kernel 1: fold projection weights; block 3 converts mw to bf16 hi/lo + mb sum.
__global__ __launch_bounds__(256) void k_prep(const float* __restrict__ cw1,
                                              const float* __restrict__ cb1,
                                              const float* __restrict__ cw2,
                                              const float* __restrict__ cb2,
                                              const float* __restrict__ mw,
                                              const float* __restrict__ mb,
                                              float* __restrict__ ws) {
    int h = blockIdx.x, t = threadIdx.x;
    __shared__ float s1[4096], s2[4096];
    if (h < 3) {
        for (int i = t; i < 4096; i += 256) {
            s1[i] = cw1[h * 4096 + i];
            s2[i] = cw2[h * 4096 + i];
        }
        __syncthreads();
        for (int i = t; i < 4096; i += 256) {
            int c2 = i >> 6, c1 = i & 63;
            float acc = 0.f;
            for (int o = 0; o < 64; o++) acc += s2[o * 64 + c2] * s1[o * 64 + c1];
            ws[OFF_W + h * 4096 + i] = acc;
        }
        if (t < 64) {
            float a = 0.f, b2 = 0.f;
            for (int o = 0; o < 64; o++) {
                a  += cb2[h * 64 + o] * s1[o * 64 + t];
                b2 += cb1[h * 64 + o] * s2[o * 64 + t];
            }
            ws[OFF_U1 + h * 64 + t] = a;
            ws[OFF_U2 + h * 64 + t] = b2;
        }
        if (t == 0) {
            float a = 0.f;
            for (int o = 0; o < 64; o++) a += cb1[h * 64 + o] * cb2[h * 64 + o];
            ws[OFF_S + h] = a;
        }
    } else {
        unsigned short* mh = (unsigned short*)(ws + OFF_MWH);
        unsigned short* ml = (unsigned short*)(ws + OFF_MWL);
        for (int i = t; i < 12288; i += 256) {
            float v = mw[i];                 // layout [h][o][c] kept as-is
            unsigned short hb = bfh(v);
            mh[i] = hb;
            ml[i] = bfh(v - bfh2f(hb));
        }
        if (t < 64) ws[OFF_MBS + t] = mb[t] + mb[64 + t] + mb[128 + t];
    }
}

// ---------------------------------------------------------------------------
// Kernel 2 (MFMA): att_m[b,h,m,n] = (sum_l X_l^T W X_l + a1[n] + a2[m] + 35*s)/2240
__global__ __launch_bounds__(256) void k_attm(float* __restrict__ ws) {
    const int b = blockIdx.x, h = blockIdx.y, t = threadIdx.x;
    const int lane = t & 63;
    const int w = __builtin_amdgcn_readfirstlane(t >> 6);   // wave 0..3
    const int lg = lane >> 4;      // k-group 0..3
    const int lr = lane & 15;      // row/col within 16-tile

    __shared__ unsigned short sXh[2][32 * 72];   // X^T hi, double-buffered
    __shared__ unsigned short sXl[2][32 * 72];   // X^T lo
    __shared__ unsigned short sPh[32 * 72];      // P^T hi  [n][c2]
    __shared__ unsigned short sPl[32 * 72];      // P^T lo
    __shared__ float sxs[64 * 25];               // sum_l X  [c][n], stride 25
    __shared__ float sA1[23], sA2[23];

    const float* xtb = ws + OFF_XT + (size_t)b * CNL;

    // --- W fragments (phase-A A-operand), hoisted: rows 16w+lr, split hi/lo ---
    bf16x8 wh[2], wl[2];
    {
        const float* Wg = ws + OFF_W + h * 4096 + (16 * w + lr) * 64;
        #pragma unroll
        for (int s = 0; s < 2; s++) {
            const float* p = Wg + 32 * s + 8 * lg;
            float4 v0 = *(const float4*)(p);
            float4 v1 = *(const float4*)(p + 4);
            float vv[8] = {v0.x, v0.y, v0.z, v0.w, v1.x, v1.y, v1.z, v1.w};
            #pragma unroll
            for (int e = 0; e < 8; e++) {
                unsigned short hb = bfh(vv[e]);
                wh[s][e] = (short)hb;
                wl[s][e] = (short)bfh(vv[e] - bfh2f(hb));
            }
        }
    }

    const int mt = w >> 1, nt = w & 1;           // phase-B tile
    f32x4 attC = {0.f, 0.f, 0.f, 0.f};
    float xs[6] = {0.f, 0.f, 0.f, 0.f, 0.f, 0.f};

    #pragma unroll 1
    for (int l = 0; l < NL; l++) {
        const int cur = l & 1;
        {
            const float* src = xtb + (size_t)l * NCN;
            unsigned short* xh = sXh[cur];
            unsigned short* xl = sXl[cur];
            #pragma unroll
            for (int j = 0; j < 6; j++) {
                int i = t + 256 * j;
                if (i < NCN) {
                    float v = src[i];
                    xs[j] += v;
                    int n = i % 23, c = i / 23;
                    unsigned short hb = bfh(v);
                    xh[n * 72 + c] = hb;
                    xl[n * 72 + c] = bfh(v - bfh2f(hb));
                }
            }
        }
        __syncthreads();   // X ready; prev-iter P consumers also done

        const unsigned short* xh = sXh[cur];
        const unsigned short* xl = sXl[cur];

        // --- phase A: P rows [16w,16w+16) x n-tiles {0,1}, K = 64 ---
        f32x4 pc[2];
        #pragma unroll
        for (int ntt = 0; ntt < 2; ntt++) {
            f32x4 c = {0.f, 0.f, 0.f, 0.f};
            #pragma unroll
            for (int s = 0; s < 2; s++) {
                int off = (ntt * 16 + lr) * 72 + 32 * s + 8 * lg;
                bf16x8 bh = *(const bf16x8*)(xh + off);
                bf16x8 bl = *(const bf16x8*)(xl + off);
                c = __builtin_amdgcn_mfma_f32_16x16x32_bf16(wh[s], bh, c, 0, 0, 0);
                c = __builtin_amdgcn_mfma_f32_16x16x32_bf16(wh[s], bl, c, 0, 0, 0);
                c = __builtin_amdgcn_mfma_f32_16x16x32_bf16(wl[s], bh, c, 0, 0, 0);
            }
            pc[ntt] = c;
        }
        #pragma unroll
        for (int ntt = 0; ntt < 2; ntt++) {
            int n = ntt * 16 + lr;
            int c2 = 16 * w + 4 * lg;
            us4 ph4, pl4;
            #pragma unroll
            for (int r = 0; r < 4; r++) {
                float v = pc[ntt][r];
                unsigned short hb = bfh(v);
                ph4[r] = hb;
                pl4[r] = bfh(v - bfh2f(hb));
            }
            *(us4*)(sPh + n * 72 + c2) = ph4;
            *(us4*)(sPl + n * 72 + c2) = pl4;
        }
        __syncthreads();   // P ready

        // --- phase B: att(mt,nt) += X^T @ P, K = 64 ---
        #pragma unroll
        for (int s = 0; s < 2; s++) {
            int aoff = (mt * 16 + lr) * 72 + 32 * s + 8 * lg;
            int boff = (nt * 16 + lr) * 72 + 32 * s + 8 * lg;
            bf16x8 ah = *(const bf16x8*)(xh + aoff);
            bf16x8 al = *(const bf16x8*)(xl + aoff);
            bf16x8 bh = *(const bf16x8*)(sPh + boff);
            bf16x8 bl = *(const bf16x8*)(sPl + boff);
            attC = __builtin_amdgcn_mfma_f32_16x16x32_bf16(ah, bh, attC, 0, 0, 0);
            attC = __builtin_amdgcn_mfma_f32_16x16x32_bf16(ah, bl, attC, 0, 0, 0);
            attC = __builtin_amdgcn_mfma_f32_16x16x32_bf16(al, bh, attC, 0, 0, 0);
        }
    }

    // --- rank-1 correction terms from exact fp32 column sums ---
    #pragma unroll
    for (int j = 0; j < 6; j++) {
        int i = t + 256 * j;
        if (i < NCN) sxs[(i / 23) * 25 + (i % 23)] = xs[j];
    }
    __syncthreads();
    if (t < 23) {
        float a = 0.f;
        const float* u = ws + OFF_U1 + h * 64;
        for (int c = 0; c < 64; c++) a += u[c] * sxs[c * 25 + t];
        sA1[t] = a;
    } else if (t >= 32 && t < 55) {
        int n = t - 32;
        float a = 0.f;
        const float* u = ws + OFF_U2 + h * 64;
        for (int c = 0; c < 64; c++) a += u[c] * sxs[c * 25 + n];
        sA2[n] = a;
    }
    __syncthreads();

    float sh = ws[OFF_S + h];
    float* o = ws + OFF_ATTM + (size_t)b * HF + h * NSQ;
    int n = nt * 16 + lr;
    if (n < 23) {
        #pragma unroll
        for (int r = 0; r < 4; r++) {
            int m = mt * 16 + 4 * lg + r;
            if (m < 23)
                o[m * 23 + n] = (attC[r] + sA1[n] + sA2[m] + 35.f * sh) * (1.f / 2240.f);
        }
    }
}

// ---------------------------------------------------------------------------
// Kernel 3: BN batch statistics per (h, feature).
__global__ __launch_bounds__(256) void k_bn(float* __restrict__ ws) {
    int f = blockIdx.x * 256 + threadIdx.x;
    if (f >= HF) return;
    const float* p = ws + OFF_ATTM + f;
    float s = 0.f, s2 = 0.f;
    for (int b = 0; b < NB; b++) {
        float v = p[b * HF];
        s += v; s2 += v * v;
    }
    float mean = s * (1.f / 256.f);
    float var  = s2 * (1.f / 256.f) - mean * mean;
    ws[OFF_MEAN + f] = mean;
    ws[OFF_RSTD + f] = rsqrtf(var + 1e-5f);
}

// ---------------------------------------------------------------------------
// Kernel 4: normalize, softmax over rows, A = A_ske + att + A_adp.
__global__ __launch_bounds__(256) void k_adp(const float* __restrict__ gamma,
                                             const float* __restrict__ beta,
                                             const float* __restrict__ att,
                                             const float* __restrict__ aske,
                                             float* __restrict__ ws) {
    int b = blockIdx.x, h = blockIdx.y, t = threadIdx.x;
    __shared__ float sv[529];
    const float* am   = ws + OFF_ATTM + b * HF + h * NSQ;
    const float* mean = ws + OFF_MEAN + h * NSQ;
    const float* rstd = ws + OFF_RSTD + h * NSQ;
    for (int i = t; i < 529; i += 256) {
        sv[i] = (am[i] - mean[i]) * rstd[i] * gamma[h * NSQ + i] + beta[h * NSQ + i];
    }
    __syncthreads();
    if (t < 23) {
        float mx = -1e30f;
        #pragma unroll
        for (int m = 0; m < 23; m++) mx = fmaxf(mx, sv[m * 23 + t]);
        float e[23];
        float sum = 0.f;
        #pragma unroll
        for (int m = 0; m < 23; m++) {
            float v = __expf(sv[m * 23 + t] - mx);
            e[m] = v; sum += v;
        }
        float inv = 1.f / sum;
        #pragma unroll
        for (int m = 0; m < 23; m++) sv[m * 23 + t] = e[m] * inv;
    }
    __syncthreads();
    float* o = ws + OFF_A + b * HF + h * NSQ;
    for (int i = t; i < 529; i += 256) {
        o[i] = sv[i] + aske[h * NSQ + i] + att[h * NSQ + i];
    }
}

// ---------------------------------------------------------------------------
// Kernel 5 (fused GCN + temporal FC), one block per batch b, 8 waves.
// Per l: phase A  S[h](64c x 23m pad32) = X_l @ A[h]   (MFMA, X split-bf16)
//        phase B  Y(64o x 23m)         = sum_h MW[h] @ S[h]  (MFMA, MW split)
//        y -> LDS bf16 [o*23+m][l pad36]
// Then:  out[b, o*23+m, :] = y @ W  (MFMA K=32 + VALU tail l=32..34) + bias
// NOTE: sS row stride MUST be >= 64 (k-dim c = 0..63); stride 72 (144 B,
// 16B-aligned rows). S stored hi-only bf16 (error budget: same order as the
// y-bf16 quantization that already passed at absmax 0.0156 vs thr 0.0812).
__global__ __launch_bounds__(512, 2) void k_fused(float* __restrict__ ws,
                                                  const float* __restrict__ wseq,
                                                  const float* __restrict__ biasp,
                                                  float* __restrict__ out) {
    const int b = blockIdx.x, t = threadIdx.x;
    const int lane = t & 63;
    const int w = __builtin_amdgcn_readfirstlane(t >> 6);   // 0..7
    const int lg = lane >> 4, lr = lane & 15;
    const int rA = w >> 1, cA = w & 1;   // row-tile (c / o), col-tile (m)

    __shared__ __align__(16) unsigned short sXh[64 * 40], sXl[64 * 40];
    __shared__ __align__(16) unsigned short sAT[3][2][32 * 40];  // A^T [m][n] hi/lo
    __shared__ __align__(16) unsigned short sS[3][32 * 72];      // S^T [m][c] hi only
    __shared__ __align__(16) unsigned short sY[1472 * 36];       // y bf16 [p][l]
    __shared__ __align__(16) unsigned short sWTh[48 * 40], sWTl[48 * 40]; // W^T [lp][l<32]
    __shared__ float sWt[3 * 35];        // W rows l=32..34
    __shared__ float sBias[35];

    const float* xtb = ws + OFF_XT + (size_t)b * CNL;
    const float* Ab  = ws + OFF_A + (size_t)b * HF;

    // ---- one-time staging (first in-loop barrier fences all of it) ----
    for (int i = t; i < 64 * 40; i += 512) {
        if ((i % 40) >= 23) { sXh[i] = 0; sXl[i] = 0; }   // K-pad of X rows
    }
    for (int i = t; i < 3 * 1280; i += 512) {
        int h = i / 1280, r2 = i - h * 1280, m = r2 / 40, n = r2 - m * 40;
        float v = (n < 23 && m < 23) ? Ab[h * 529 + n * 23 + m] : 0.f;
        unsigned short hb = bfh(v);
        sAT[h][0][m * 40 + n] = hb;
        sAT[h][1][m * 40 + n] = bfh(v - bfh2f(hb));
    }
    for (int i = t; i < 48 * 40; i += 512) {
        int lp = i / 40, l = i - lp * 40;
        float v = (lp < 35 && l < 32) ? wseq[l * 35 + lp] : 0.f;
        unsigned short hb = bfh(v);
        sWTh[i] = hb;
        sWTl[i] = bfh(v - bfh2f(hb));
    }
    if (t < 105) sWt[t] = wseq[(32 + t / 35) * 35 + (t % 35)];
    if (t >= 128 && t < 163) sBias[t - 128] = biasp[t - 128];

    // ---- MW fragments (phase-B A-operand), register-resident ----
    const unsigned short* mwh = (const unsigned short*)(ws + OFF_MWH);
    const unsigned short* mwl = (const unsigned short*)(ws + OFF_MWL);
    bf16x8 fwh[3][2], fwl[3][2];
    #pragma unroll
    for (int h = 0; h < 3; h++)
        #pragma unroll
        for (int s = 0; s < 2; s++) {
            int off = h * 4096 + (16 * rA + lr) * 64 + 32 * s + 8 * lg;
            fwh[h][s] = *(const bf16x8*)(mwh + off);
            fwl[h][s] = *(const bf16x8*)(mwl + off);
        }
    float4 mbsv = *(const float4*)(ws + OFF_MBS + 16 * rA + 4 * lg);
    float mb4[4] = {mbsv.x, mbsv.y, mbsv.z, mbsv.w};

    const f32x4 zf = {0.f, 0.f, 0.f, 0.f};

    #pragma unroll 1
    for (int l = 0; l < NL; l++) {
        // stage X_l (coalesced fp32, split hi/lo)
        const float* src = xtb + l * NCN;
        #pragma unroll
        for (int j = 0; j < 3; j++) {
            int i = t + 512 * j;
            if (i < NCN) {
                float v = src[i];
                int c = i / 23, n = i - c * 23;
                unsigned short hb = bfh(v);
                sXh[c * 40 + n] = hb;
                sXl[c * 40 + n] = bfh(v - bfh2f(hb));
            }
        }
        __syncthreads();   // X ready (also fences prior phase-B S reads)

        // ---- phase A: S[h] = X_l @ A[h]; wave (rA,cA) -> rows 16rA.., cols 16cA.. ----
        #pragma unroll
        for (int h = 0; h < 3; h++) {
            bf16x8 xah = *(const bf16x8*)(sXh + (16 * rA + lr) * 40 + 8 * lg);
            bf16x8 xal = *(const bf16x8*)(sXl + (16 * rA + lr) * 40 + 8 * lg);
            bf16x8 ath = *(const bf16x8*)(&sAT[h][0][(16 * cA + lr) * 40 + 8 * lg]);
            bf16x8 atl = *(const bf16x8*)(&sAT[h][1][(16 * cA + lr) * 40 + 8 * lg]);
            f32x4 c0 = __builtin_amdgcn_mfma_f32_16x16x32_bf16(xah, ath, zf, 0, 0, 0);
            f32x4 c1 = __builtin_amdgcn_mfma_f32_16x16x32_bf16(xah, atl, zf, 0, 0, 0);
            c1 = __builtin_amdgcn_mfma_f32_16x16x32_bf16(xal, ath, c1, 0, 0, 0);
            us4 sh4;
            #pragma unroll
            for (int r = 0; r < 4; r++) sh4[r] = bfh(c0[r] + c1[r]);
            *(us4*)(&sS[h][(16 * cA + lr) * 72 + 16 * rA + 4 * lg]) = sh4;
        }
        __syncthreads();   // S ready

        // ---- phase B: Y = sum_h MW[h] @ S[h]; two accumulators break the chain ----
        f32x4 Yh = zf, Yc = zf;
        #pragma unroll
        for (int h = 0; h < 3; h++)
            #pragma unroll
            for (int s = 0; s < 2; s++) {
                bf16x8 bh = *(const bf16x8*)(&sS[h][(16 * cA + lr) * 72 + 32 * s + 8 * lg]);
                Yh = __builtin_amdgcn_mfma_f32_16x16x32_bf16(fwh[h][s], bh, Yh, 0, 0, 0);
                Yc = __builtin_amdgcn_mfma_f32_16x16x32_bf16(fwl[h][s], bh, Yc, 0, 0, 0);
            }
        int m = 16 * cA + lr;
        if (m < 23) {
            #pragma unroll
            for (int r = 0; r < 4; r++) {
                int o = 16 * rA + 4 * lg + r;
                float yv = Yh[r] + Yc[r] + mb4[r];
                sY[(o * 23 + m) * 36 + l] = bfh(yv);
            }
        }
    }
    __syncthreads();   // sY complete

    // ---- temporal FC: 92 p-tiles x 3 lp-tiles, K=32 MFMA + tail l=32..34 ----
    #pragma unroll 1
    for (int tt = w; tt < 276; tt += 8) {
        int pt = tt / 3, lt = tt - pt * 3;
        int pA = 16 * pt + lr;
        // A-frag (y row pA, k=l 8lg..8lg+7) via two 8B reads (stride 36 shorts)
        us4 a0 = *(const us4*)(sY + pA * 36 + 8 * lg);
        us4 a1 = *(const us4*)(sY + pA * 36 + 8 * lg + 4);
        union { bf16x8 v; us4 h2[2]; } au;
        au.h2[0] = a0; au.h2[1] = a1;
        bf16x8 wbh = *(const bf16x8*)(sWTh + (16 * lt + lr) * 40 + 8 * lg);
        bf16x8 wbl = *(const bf16x8*)(sWTl + (16 * lt + lr) * 40 + 8 * lg);
        f32x4 c0 = __builtin_amdgcn_mfma_f32_16x16x32_bf16(au.v, wbh, zf, 0, 0, 0);
        f32x4 c1 = __builtin_amdgcn_mfma_f32_16x16x32_bf16(au.v, wbl, zf, 0, 0, 0);
        int lpc = 16 * lt + lr;        // C col
        if (lpc < 35) {
            float wt0 = sWt[lpc], wt1 = sWt[35 + lpc], wt2 = sWt[70 + lpc];
            float bv = sBias[lpc];
            #pragma unroll
            for (int r = 0; r < 4; r++) {
                int pr = 16 * pt + 4 * lg + r;
                us4 yt = *(const us4*)(sY + pr * 36 + 32);   // l=32,33,34 (+1 pad)
                float v = c0[r] + c1[r] + bv
                        + bfh2f(yt[0]) * wt0 + bfh2f(yt[1]) * wt1 + bfh2f(yt[2]) * wt2;
                out[((size_t)b * 1472 + pr) * 35 + lpc] = v;
            }
        }
    }
}

// ---------------------------------------------------------------------------
extern "C" void kernel_launch(void* const* d_in, const int* in_sizes, int n_in,
                              void* d_out, int out_size, void* d_ws, size_t ws_size,
                              hipStream_t stream) {
    const float* x    = (const float*)d_in[0];
    const float* cw1  = (const float*)d_in[1];
    const float* cb1  = (const float*)d_in[2];
    const float* cw2  = (const float*)d_in[3];
    const float* cb2  = (const float*)d_in[4];
    const float* gam  = (const float*)d_in[5];
    const float* bet  = (const float*)d_in[6];
    const float* mw   = (const float*)d_in[7];
    const float* mb   = (const float*)d_in[8];
    const float* att  = (const float*)d_in[9];
    const float* aske = (const float*)d_in[10];
    const float* wsq  = (const float*)d_in[11];
    const float* bias = (const float*)d_in[12];
    float* ws = (float*)d_ws;
    float* out = (float*)d_out;

    hipLaunchKernelGGL(k_prep, dim3(4),       dim3(256),  0, stream, cw1, cb1, cw2, cb2, mw, mb, ws);
    hipLaunchKernelGGL(k_xt,   dim3(256),     dim3(1024), 0, stream, x, ws);
    hipLaunchKernelGGL(k_attm, dim3(256, 3),  dim3(256),  0, stream, ws);
    hipLaunchKernelGGL(k_bn,   dim3(7),       dim3(256),  0, stream, ws);
    hipLaunchKernelGGL(k_adp,  dim3(256, 3),  dim3(256),  0, stream, gam, bet, att, aske, ws);
    hipLaunchKernelGGL(k_fused, dim3(256),    dim3(512),  0, stream, ws, wsq, bias, out);
}

// Round 4
// 275.037 us; speedup vs baseline: 3.5375x; 1.1737x over previous
//
#include <hip/hip_runtime.h>
#include <hip/hip_bf16.h>

typedef __hip_bfloat16 bf16;
typedef __attribute__((ext_vector_type(8))) short bf16x8;
typedef __attribute__((ext_vector_type(4))) float f32x4;
typedef __attribute__((ext_vector_type(4))) unsigned short us4;
typedef __attribute__((ext_vector_type(8))) unsigned short us8;

// Problem constants
#define NB   256           // batch
#define NN   23            // nodes
#define NL   35            // seq len
#define NNL  805           // NN*NL
#define CNL  51520         // NC*NNL (per-batch x elements)
#define NSQ  529           // NN*NN
#define HF   1587          // NH*NSQ
#define NCN  1472          // 64*23 (one X_l slice)

// ws layout (float offsets)
#define OFF_W     0         // [3][64][64]
#define OFF_U1    12288
#define OFF_U2    12480
#define OFF_S     12672
#define OFF_ATTM  12800     // [256][1587]
#define OFF_MEAN  419072
#define OFF_RSTD  420672
#define OFF_A     422272    // [256][1587] -> 828544
#define OFF_MWH   828544    // mw bf16 hi [3][64o][64c] (12288 shorts)
#define OFF_MWL   834688    // mw bf16 lo
#define OFF_MBS   840832    // mbsum[64] -> pad 840960
#define OFF_XTB   840960    // X^T bf16 hi/lo [256][35][2 planes][23n][64c]
                            // = 256*35*2944 shorts = 52.8 MB -> end 14,030,080 floats
// total ~56.1 MB (same as round 3)

// split-bf16 helpers: x = hi + lo, each exactly representable in bf16
__device__ inline unsigned short bfh(float x) {
    unsigned u = __float_as_uint(x);
    return (unsigned short)((u + 0x7FFFu + ((u >> 16) & 1u)) >> 16);  // RNE
}
__device__ inline float bfh2f(unsigned short h) {
    return __uint_as_float(((unsigned)h) << 16);
}

// ---------------------------------------------------------------------------
// Kernel 0: transpose x[b][c][n][l] -> X^T bf16 hi/lo [b][l][p][n][c].
// Stages half the l's with all channels in LDS; emits contiguous 16B chunks.
__global__ __launch_bounds__(1024) void k_xt(const float* __restrict__ x,
                                             float* __restrict__ ws) {
    int b = blockIdx.x, t = threadIdx.x;
    __shared__ float sx[64 * 23 * 18];   // 106 KB
    const float* xb = x + b * CNL;
    unsigned short* xo = (unsigned short*)(ws + OFF_XTB) + (size_t)b * NL * 2944;
    for (int lh = 0; lh < 2; lh++) {
        int l0 = lh * 18, Lc = lh ? 17 : 18;
        if (lh) __syncthreads();
        for (int i = t; i < 1472 * Lc; i += 1024) {
            int cn = i / Lc, li = i - cn * Lc;        // cn = c*23+n
            sx[cn * 18 + li] = xb[cn * 35 + l0 + li];
        }
        __syncthreads();
        // one item = 16B chunk: row n, cols c=8k..8k+7 of slice l0+li
        for (int item = t; item < 184 * Lc; item += 1024) {
            int li = item / 184, rem = item - li * 184;
            int n = rem >> 3, k = rem & 7;
            us8 hi, lo;
            #pragma unroll
            for (int e = 0; e < 8; e++) {
                float v = sx[((8 * k + e) * 23 + n) * 18 + li];
                unsigned short hb = bfh(v);
                hi[e] = hb;
                lo[e] = bfh(v - bfh2f(hb));
            }
            unsigned short* dst = xo + (size_t)(l0 + li) * 2944 + n * 64 + 8 * k;
            *(us8*)(dst) = hi;           // plane hi
            *(us8*)(dst + 1472) = lo;    // plane lo
        }
    }
}

// ---------------------------------------------------------------------------
// Kernel 1: fold projection weights; block 3 converts mw to bf16 hi/lo + mb sum.
__global__ __launch_bounds__(256) void k_prep(const float* __restrict__ cw1,
                                              const float* __restrict__ cb1,
                                              const float* __restrict__ cw2,
                                              const float* __restrict__ cb2,
                                              const float* __restrict__ mw,
                                              const float* __restrict__ mb,
                                              float* __restrict__ ws) {
    int h = blockIdx.x, t = threadIdx.x;
    __shared__ float s1[4096], s2[4096];
    if (h < 3) {
        for (int i = t; i < 4096; i += 256) {
            s1[i] = cw1[h * 4096 + i];
            s2[i] = cw2[h * 4096 + i];
        }
        __syncthreads();
        for (int i = t; i < 4096; i += 256) {
            int c2 = i >> 6, c1 = i & 63;
            float acc = 0.f;
            for (int o = 0; o < 64; o++) acc += s2[o * 64 + c2] * s1[o * 64 + c1];
            ws[OFF_W + h * 4096 + i] = acc;
        }
        if (t < 64) {
            float a = 0.f, b2 = 0.f;
            for (int o = 0; o < 64; o++) {
                a  += cb2[h * 64 + o] * s1[o * 64 + t];
                b2 += cb1[h * 64 + o] * s2[o * 64 + t];
            }
            ws[OFF_U1 + h * 64 + t] = a;
            ws[OFF_U2 + h * 64 + t] = b2;
        }
        if (t == 0) {
            float a = 0.f;
            for (int o = 0; o < 64; o++) a += cb1[h * 64 + o] * cb2[h * 64 + o];
            ws[OFF_S + h] = a;
        }
    } else {
        unsigned short* mh = (unsigned short*)(ws + OFF_MWH);
        unsigned short* ml = (unsigned short*)(ws + OFF_MWL);
        for (int i = t; i < 12288; i += 256) {
            float v = mw[i];                 // layout [h][o][c]
            unsigned short hb = bfh(v);
            mh[i] = hb;
            ml[i] = bfh(v - bfh2f(hb));
        }
        if (t < 64) ws[OFF_MBS + t] = mb[t] + mb[64 + t] + mb[128 + t];
    }
}

// ---------------------------------------------------------------------------
// Kernel 2 (MFMA): att_m[b,h,m,n] = (sum_l X_l^T W X_l + a1[n] + a2[m] + 35*s)/2240
// Staging now: pre-split bf16 chunks from global, us8 load + ds_write_b128.
__global__ __launch_bounds__(256) void k_attm(float* __restrict__ ws) {
    const int b = blockIdx.x, h = blockIdx.y, t = threadIdx.x;
    const int lane = t & 63;
    const int w = __builtin_amdgcn_readfirstlane(t >> 6);   // wave 0..3
    const int lg = lane >> 4;      // k-group 0..3
    const int lr = lane & 15;      // row/col within 16-tile

    __shared__ unsigned short sXh[2][32 * 72];   // X^T hi, double-buffered
    __shared__ unsigned short sXl[2][32 * 72];   // X^T lo
    __shared__ unsigned short sPh[32 * 72];      // P^T hi  [n][c2]
    __shared__ unsigned short sPl[32 * 72];      // P^T lo
    __shared__ float sxs[64 * 25];               // sum_l X  [c][n], stride 25
    __shared__ float sA1[23], sA2[23];

    const unsigned short* xthl = (const unsigned short*)(ws + OFF_XTB);

    // --- W fragments (phase-A A-operand), hoisted: rows 16w+lr, split hi/lo ---
    bf16x8 wh[2], wl[2];
    {
        const float* Wg = ws + OFF_W + h * 4096 + (16 * w + lr) * 64;
        #pragma unroll
        for (int s = 0; s < 2; s++) {
            const float* p = Wg + 32 * s + 8 * lg;
            float4 v0 = *(const float4*)(p);
            float4 v1 = *(const float4*)(p + 4);
            float vv[8] = {v0.x, v0.y, v0.z, v0.w, v1.x, v1.y, v1.z, v1.w};
            #pragma unroll
            for (int e = 0; e < 8; e++) {
                unsigned short hb = bfh(vv[e]);
                wh[s][e] = (short)hb;
                wl[s][e] = (short)bfh(vv[e] - bfh2f(hb));
            }
        }
    }

    // --- staging chunk decomposition (368 = 2 planes x 23 rows x 8 chunks) ---
    const int j1 = t;                              // chunk 1 (all threads)
    const int p1 = j1 / 184, r1 = j1 - p1 * 184;
    const int n1 = r1 >> 3, k1 = r1 & 7;
    unsigned short* d1 = (p1 ? sXl[0] : sXh[0]) + n1 * 72 + 8 * k1;
    const int j2 = 256 + t;                        // chunk 2 (t<112, plane lo)
    const int r2 = j2 - 184;
    const int n2 = r2 >> 3, k2 = r2 & 7;
    unsigned short* d2 = sXl[0] + n2 * 72 + 8 * k2;

    const int mt = w >> 1, nt = w & 1;             // phase-B tile
    f32x4 attC = {0.f, 0.f, 0.f, 0.f};
    float xa1[8] = {0, 0, 0, 0, 0, 0, 0, 0};
    float xa2[8] = {0, 0, 0, 0, 0, 0, 0, 0};

    #pragma unroll 1
    for (int l = 0; l < NL; l++) {
        const int cur = l & 1;
        {
            const us8* g = (const us8*)(xthl + (size_t)(b * NL + l) * 2944);
            us8 v1 = g[j1];
            *(us8*)(d1 + cur * 2304) = v1;
            #pragma unroll
            for (int e = 0; e < 8; e++) xa1[e] += bfh2f(v1[e]);
            if (t < 112) {
                us8 v2 = g[j2];
                *(us8*)(d2 + cur * 2304) = v2;
                #pragma unroll
                for (int e = 0; e < 8; e++) xa2[e] += bfh2f(v2[e]);
            }
        }
        __syncthreads();   // X ready; prev-iter P consumers also done

        const unsigned short* xh = sXh[cur];
        const unsigned short* xl = sXl[cur];

        // --- phase A: P rows [16w,16w+16) x n-tiles {0,1}, K = 64 ---
        f32x4 pc[2];
        #pragma unroll
        for (int ntt = 0; ntt < 2; ntt++) {
            f32x4 c = {0.f, 0.f, 0.f, 0.f};
            #pragma unroll
            for (int s = 0; s < 2; s++) {
                int off = (ntt * 16 + lr) * 72 + 32 * s + 8 * lg;
                bf16x8 bh = *(const bf16x8*)(xh + off);
                bf16x8 bl = *(const bf16x8*)(xl + off);
                c = __builtin_amdgcn_mfma_f32_16x16x32_bf16(wh[s], bh, c, 0, 0, 0);
                c = __builtin_amdgcn_mfma_f32_16x16x32_bf16(wh[s], bl, c, 0, 0, 0);
                c = __builtin_amdgcn_mfma_f32_16x16x32_bf16(wl[s], bh, c, 0, 0, 0);
            }
            pc[ntt] = c;
        }
        #pragma unroll
        for (int ntt = 0; ntt < 2; ntt++) {
            int n = ntt * 16 + lr;
            int c2 = 16 * w + 4 * lg;
            us4 ph4, pl4;
            #pragma unroll
            for (int r = 0; r < 4; r++) {
                float v = pc[ntt][r];
                unsigned short hb = bfh(v);
                ph4[r] = hb;
                pl4[r] = bfh(v - bfh2f(hb));
            }
            *(us4*)(sPh + n * 72 + c2) = ph4;
            *(us4*)(sPl + n * 72 + c2) = pl4;
        }
        __syncthreads();   // P ready

        // --- phase B: att(mt,nt) += X^T @ P, K = 64 ---
        #pragma unroll
        for (int s = 0; s < 2; s++) {
            int aoff = (mt * 16 + lr) * 72 + 32 * s + 8 * lg;
            int boff = (nt * 16 + lr) * 72 + 32 * s + 8 * lg;
            bf16x8 ah = *(const bf16x8*)(xh + aoff);
            bf16x8 al = *(const bf16x8*)(xl + aoff);
            bf16x8 bh = *(const bf16x8*)(sPh + boff);
            bf16x8 bl = *(const bf16x8*)(sPl + boff);
            attC = __builtin_amdgcn_mfma_f32_16x16x32_bf16(ah, bh, attC, 0, 0, 0);
            attC = __builtin_amdgcn_mfma_f32_16x16x32_bf16(ah, bl, attC, 0, 0, 0);
            attC = __builtin_amdgcn_mfma_f32_16x16x32_bf16(al, bh, attC, 0, 0, 0);
        }
    }

    // --- rank-1 correction terms from hi+lo column sums ---
    if (t < 184) {          // hi-plane chunks cover all (c,n) exactly once
        #pragma unroll
        for (int e = 0; e < 8; e++) sxs[(8 * k1 + e) * 25 + n1] = xa1[e];
    }
    __syncthreads();
    if (t >= 184) {         // lo chunks 0..71
        #pragma unroll
        for (int e = 0; e < 8; e++) sxs[(8 * k1 + e) * 25 + n1] += xa1[e];
    }
    if (t < 112) {          // lo chunks 72..183
        #pragma unroll
        for (int e = 0; e < 8; e++) sxs[(8 * k2 + e) * 25 + n2] += xa2[e];
    }
    __syncthreads();
    if (t < 23) {
        float a = 0.f;
        const float* u = ws + OFF_U1 + h * 64;
        for (int c = 0; c < 64; c++) a += u[c] * sxs[c * 25 + t];
        sA1[t] = a;
    } else if (t >= 32 && t < 55) {
        int n = t - 32;
        float a = 0.f;
        const float* u = ws + OFF_U2 + h * 64;
        for (int c = 0; c < 64; c++) a += u[c] * sxs[c * 25 + n];
        sA2[n] = a;
    }
    __syncthreads();

    float sh = ws[OFF_S + h];
    float* o = ws + OFF_ATTM + (size_t)b * HF + h * NSQ;
    int n = nt * 16 + lr;
    if (n < 23) {
        #pragma unroll
        for (int r = 0; r < 4; r++) {
            int m = mt * 16 + 4 * lg + r;
            if (m < 23)
                o[m * 23 + n] = (attC[r] + sA1[n] + sA2[m] + 35.f * sh) * (1.f / 2240.f);
        }
    }
}

// ---------------------------------------------------------------------------
// Kernel 3: BN batch statistics per (h, feature).
__global__ __launch_bounds__(256) void k_bn(float* __restrict__ ws) {
    int f = blockIdx.x * 256 + threadIdx.x;
    if (f >= HF) return;
    const float* p = ws + OFF_ATTM + f;
    float s = 0.f, s2 = 0.f;
    for (int b = 0; b < NB; b++) {
        float v = p[b * HF];
        s += v; s2 += v * v;
    }
    float mean = s * (1.f / 256.f);
    float var  = s2 * (1.f / 256.f) - mean * mean;
    ws[OFF_MEAN + f] = mean;
    ws[OFF_RSTD + f] = rsqrtf(var + 1e-5f);
}

// ---------------------------------------------------------------------------
// Kernel 4: normalize, softmax over rows, A = A_ske + att + A_adp.
__global__ __launch_bounds__(256) void k_adp(const float* __restrict__ gamma,
                                             const float* __restrict__ beta,
                                             const float* __restrict__ att,
                                             const float* __restrict__ aske,
                                             float* __restrict__ ws) {
    int b = blockIdx.x, h = blockIdx.y, t = threadIdx.x;
    __shared__ float sv[529];
    const float* am   = ws + OFF_ATTM + b * HF + h * NSQ;
    const float* mean = ws + OFF_MEAN + h * NSQ;
    const float* rstd = ws + OFF_RSTD + h * NSQ;
    for (int i = t; i < 529; i += 256) {
        sv[i] = (am[i] - mean[i]) * rstd[i] * gamma[h * NSQ + i] + beta[h * NSQ + i];
    }
    __syncthreads();
    if (t < 23) {
        float mx = -1e30f;
        #pragma unroll
        for (int m = 0; m < 23; m++) mx = fmaxf(mx, sv[m * 23 + t]);
        float e[23];
        float sum = 0.f;
        #pragma unroll
        for (int m = 0; m < 23; m++) {
            float v = __expf(sv[m * 23 + t] - mx);
            e[m] = v; sum += v;
        }
        float inv = 1.f / sum;
        #pragma unroll
        for (int m = 0; m < 23; m++) sv[m * 23 + t] = e[m] * inv;
    }
    __syncthreads();
    float* o = ws + OFF_A + b * HF + h * NSQ;
    for (int i = t; i < 529; i += 256) {
        o[i] = sv[i] + aske[h * NSQ + i] + att[h * NSQ + i];
    }
}

// ---------------------------------------------------------------------------
// Kernel 5 (fused GCN + temporal FC), one block per batch b, 8 waves.
// Reassociated: Y = sum_h (MW[h] @ X) @ A[h].
// Per l: phase A'  T^T(32n x 64o per h) = X^T @ MW^T  -> write T[o][n] (us4)
//        phase B'  Y(64o x 23m) = sum_h T[h] @ A[h]   (K = n = 32, sAT zero-padded)
//        y -> LDS bf16 [o*23+m][l pad36]
// Then:  out[b, o*23+m, :] = y @ W  (MFMA K=32 + VALU tail l=32..34) + bias
// X consumed from the SAME pre-split [n][c] global layout as k_attm.
__global__ __launch_bounds__(512, 2) void k_fused(float* __restrict__ ws,
                                                  const float* __restrict__ wseq,
                                                  const float* __restrict__ biasp,
                                                  float* __restrict__ out) {
    const int b = blockIdx.x, t = threadIdx.x;
    const int lane = t & 63;
    const int w = __builtin_amdgcn_readfirstlane(t >> 6);   // 0..7
    const int lg = lane >> 4, lr = lane & 15;
    const int nt = w >> 2, ot = w & 3;     // phase A' tile (n-tile, o-tile)
    const int ot2 = w >> 1, mt = w & 1;    // phase B' tile (o-tile, m-tile)

    __shared__ __align__(16) unsigned short sXh[32 * 72], sXl[32 * 72];
    __shared__ __align__(16) unsigned short sAT[3][2][32 * 40];  // A^T [m][n] hi/lo
    __shared__ __align__(16) unsigned short sT[3][64 * 40];      // T [o][n] hi only
    __shared__ __align__(16) unsigned short sY[1472 * 36];       // y bf16 [p][l]
    __shared__ __align__(16) unsigned short sWTh[48 * 40], sWTl[48 * 40]; // W^T [lp][l<32]
    __shared__ float sWt[3 * 35];        // W rows l=32..34
    __shared__ float sBias[35];

    const unsigned short* xthl = (const unsigned short*)(ws + OFF_XTB);
    const float* Ab  = ws + OFF_A + (size_t)b * HF;

    // ---- one-time: zero sX rows 23..31 (they feed phase B's K-dim via T) ----
    for (int i = t; i < 9 * 72; i += 512) {
        sXh[23 * 72 + i] = 0;
        sXl[23 * 72 + i] = 0;
    }
    // ---- one-time staging (first in-loop barrier fences all of it) ----
    for (int i = t; i < 3 * 1280; i += 512) {
        int h = i / 1280, r2 = i - h * 1280, m = r2 / 40, n = r2 - m * 40;
        float v = (n < 23 && m < 23) ? Ab[h * 529 + n * 23 + m] : 0.f;
        unsigned short hb = bfh(v);
        sAT[h][0][m * 40 + n] = hb;
        sAT[h][1][m * 40 + n] = bfh(v - bfh2f(hb));
    }
    for (int i = t; i < 48 * 40; i += 512) {
        int lp = i / 40, l = i - lp * 40;
        float v = (lp < 35 && l < 32) ? wseq[l * 35 + lp] : 0.f;
        unsigned short hb = bfh(v);
        sWTh[i] = hb;
        sWTl[i] = bfh(v - bfh2f(hb));
    }
    if (t < 105) sWt[t] = wseq[(32 + t / 35) * 35 + (t % 35)];
    if (t >= 128 && t < 163) sBias[t - 128] = biasp[t - 128];

    // ---- MW fragments as phase-A' B-operand (MW^T cols o = MW rows o) ----
    const unsigned short* mwh = (const unsigned short*)(ws + OFF_MWH);
    const unsigned short* mwl = (const unsigned short*)(ws + OFF_MWL);
    bf16x8 fwh[3][2], fwl[3][2];
    #pragma unroll
    for (int h = 0; h < 3; h++)
        #pragma unroll
        for (int s = 0; s < 2; s++) {
            int off = h * 4096 + (16 * ot + lr) * 64 + 32 * s + 8 * lg;
            fwh[h][s] = *(const bf16x8*)(mwh + off);
            fwl[h][s] = *(const bf16x8*)(mwl + off);
        }
    float4 mbsv = *(const float4*)(ws + OFF_MBS + 16 * ot2 + 4 * lg);
    float mb4[4] = {mbsv.x, mbsv.y, mbsv.z, mbsv.w};

    // staging chunk decomposition (t < 368 active)
    const int p1 = t / 184, r1 = t - p1 * 184;
    const int n1 = r1 >> 3, k1 = r1 & 7;
    unsigned short* d1 = (p1 ? sXl : sXh) + n1 * 72 + 8 * k1;

    const f32x4 zf = {0.f, 0.f, 0.f, 0.f};

    #pragma unroll 1
    for (int l = 0; l < NL; l++) {
        if (t < 368) {
            const us8* g = (const us8*)(xthl + (size_t)(b * NL + l) * 2944);
            *(us8*)d1 = g[t];
        }
        __syncthreads();   // X ready; all waves past phase B'(l-1)

        // ---- phase A': T^T = X^T @ MW^T per h; M=n, N=o, K=c=64 ----
        bf16x8 xh0 = *(const bf16x8*)(sXh + (16 * nt + lr) * 72 + 8 * lg);
        bf16x8 xh1 = *(const bf16x8*)(sXh + (16 * nt + lr) * 72 + 32 + 8 * lg);
        bf16x8 xl0 = *(const bf16x8*)(sXl + (16 * nt + lr) * 72 + 8 * lg);
        bf16x8 xl1 = *(const bf16x8*)(sXl + (16 * nt + lr) * 72 + 32 + 8 * lg);
        #pragma unroll
        for (int h = 0; h < 3; h++) {
            f32x4 cH = __builtin_amdgcn_mfma_f32_16x16x32_bf16(xh0, fwh[h][0], zf, 0, 0, 0);
            cH = __builtin_amdgcn_mfma_f32_16x16x32_bf16(xh1, fwh[h][1], cH, 0, 0, 0);
            f32x4 cC = __builtin_amdgcn_mfma_f32_16x16x32_bf16(xh0, fwl[h][0], zf, 0, 0, 0);
            cC = __builtin_amdgcn_mfma_f32_16x16x32_bf16(xh1, fwl[h][1], cC, 0, 0, 0);
            cC = __builtin_amdgcn_mfma_f32_16x16x32_bf16(xl0, fwh[h][0], cC, 0, 0, 0);
            cC = __builtin_amdgcn_mfma_f32_16x16x32_bf16(xl1, fwh[h][1], cC, 0, 0, 0);
            // C: row = n (4lg+r within tile), col = o (lr) -> write T[o][n0..n0+3]
            us4 t4;
            #pragma unroll
            for (int r = 0; r < 4; r++) t4[r] = bfh(cH[r] + cC[r]);
            *(us4*)(&sT[h][(16 * ot + lr) * 40 + 16 * nt + 4 * lg]) = t4;
        }
        __syncthreads();   // T ready

        // ---- phase B': Y(ot2,mt) = sum_h T[h] @ A[h]; K = n = 32 ----
        f32x4 Yh = zf, Yc = zf;
        #pragma unroll
        for (int h = 0; h < 3; h++) {
            bf16x8 ta = *(const bf16x8*)(&sT[h][(16 * ot2 + lr) * 40 + 8 * lg]);
            bf16x8 ah = *(const bf16x8*)(&sAT[h][0][(16 * mt + lr) * 40 + 8 * lg]);
            bf16x8 al = *(const bf16x8*)(&sAT[h][1][(16 * mt + lr) * 40 + 8 * lg]);
            Yh = __builtin_amdgcn_mfma_f32_16x16x32_bf16(ta, ah, Yh, 0, 0, 0);
            Yc = __builtin_amdgcn_mfma_f32_16x16x32_bf16(ta, al, Yc, 0, 0, 0);
        }
        int m = 16 * mt + lr;
        if (m < 23) {
            #pragma unroll
            for (int r = 0; r < 4; r++) {
                int o = 16 * ot2 + 4 * lg + r;
                float yv = Yh[r] + Yc[r] + mb4[r];
                sY[(o * 23 + m) * 36 + l] = bfh(yv);
            }
        }
    }
    __syncthreads();   // sY complete

    // ---- temporal FC: 92 p-tiles x 3 lp-tiles, K=32 MFMA + tail l=32..34 ----
    #pragma unroll 1
    for (int tt = w; tt < 276; tt += 8) {
        int pt = tt / 3, lt = tt - pt * 3;
        int pA = 16 * pt + lr;
        us4 a0 = *(const us4*)(sY + pA * 36 + 8 * lg);
        us4 a1 = *(const us4*)(sY + pA * 36 + 8 * lg + 4);
        union { bf16x8 v; us4 h2[2]; } au;
        au.h2[0] = a0; au.h2[1] = a1;
        bf16x8 wbh = *(const bf16x8*)(sWTh + (16 * lt + lr) * 40 + 8 * lg);
        bf16x8 wbl = *(const bf16x8*)(sWTl + (16 * lt + lr) * 40 + 8 * lg);
        f32x4 c0 = __builtin_amdgcn_mfma_f32_16x16x32_bf16(au.v, wbh, zf, 0, 0, 0);
        f32x4 c1 = __builtin_amdgcn_mfma_f32_16x16x32_bf16(au.v, wbl, zf, 0, 0, 0);
        int lpc = 16 * lt + lr;
        if (lpc < 35) {
            float wt0 = sWt[lpc], wt1 = sWt[35 + lpc], wt2 = sWt[70 + lpc];
            float bv = sBias[lpc];
            #pragma unroll
            for (int r = 0; r < 4; r++) {
                int pr = 16 * pt + 4 * lg + r;
                us4 yt = *(const us4*)(sY + pr * 36 + 32);   // l=32,33,34 (+1 pad)
                float v = c0[r] + c1[r] + bv
                        + bfh2f(yt[0]) * wt0 + bfh2f(yt[1]) * wt1 + bfh2f(yt[2]) * wt2;
                out[((size_t)b * 1472 + pr) * 35 + lpc] = v;
            }
        }
    }
}

// ---------------------------------------------------------------------------
extern "C" void kernel_launch(void* const* d_in, const int* in_sizes, int n_in,
                              void* d_out, int out_size, void* d_ws, size_t ws_size,
                              hipStream_t stream) {
    const float* x    = (const float*)d_in[0];
    const float* cw1  = (const float*)d_in[1];
    const float* cb1  = (const float*)d_in[2];
    const float* cw2  = (const float*)d_in[3];
    const float* cb2  = (const float*)d_in[4];
    const float* gam  = (const float*)d_in[5];
    const float* bet  = (const float*)d_in[6];
    const float* mw   = (const float*)d_in[7];
    const float* mb   = (const float*)d_in[8];
    const float* att  = (const float*)d_in[9];
    const float* aske = (const float*)d_in[10];
    const float* wsq  = (const float*)d_in[11];
    const float* bias = (const float*)d_in[12];
    float* ws = (float*)d_ws;
    float* out = (float*)d_out;

    hipLaunchKernelGGL(k_prep, dim3(4),       dim3(256),  0, stream, cw1, cb1, cw2, cb2, mw, mb, ws);
    hipLaunchKernelGGL(k_xt,   dim3(256),     dim3(1024), 0, stream, x, ws);
    hipLaunchKernelGGL(k_attm, dim3(256, 3),  dim3(256),  0, stream, ws);
    hipLaunchKernelGGL(k_bn,   dim3(7),       dim3(256),  0, stream, ws);
    hipLaunchKernelGGL(k_adp,  dim3(256, 3),  dim3(256),  0, stream, gam, bet, att, aske, ws);
    hipLaunchKernelGGL(k_fused, dim3(256),    dim3(512),  0, stream, ws, wsq, bias, out);
}

// Round 5
// 253.049 us; speedup vs baseline: 3.8449x; 1.0869x over previous
//
#include <hip/hip_runtime.h>
#include <hip/hip_bf16.h>

typedef __hip_bfloat16 bf16;
typedef __attribute__((ext_vector_type(8))) short bf16x8;
typedef __attribute__((ext_vector_type(4))) float f32x4;
typedef __attribute__((ext_vector_type(4))) unsigned short us4;
typedef __attribute__((ext_vector_type(8))) unsigned short us8;

// Problem constants
#define NB   256           // batch
#define NN   23            // nodes
#define NL   35            // seq len
#define NNL  805           // NN*NL
#define CNL  51520         // NC*NNL (per-batch x elements)
#define NSQ  529           // NN*NN
#define HF   1587          // NH*NSQ
#define NCN  1472          // 64*23 (one X_l slice)

// ws layout (float offsets)
#define OFF_W     0         // [3][64][64]
#define OFF_U1    12288
#define OFF_U2    12480
#define OFF_S     12672
#define OFF_ATTM  12800     // [256][1587]
#define OFF_MEAN  419072
#define OFF_RSTD  420672
#define OFF_A     422272    // [256][1587] -> 828544
#define OFF_MWH   828544    // mw bf16 hi [3][64o][64c] (12288 shorts)
#define OFF_MWL   834688    // mw bf16 lo
#define OFF_MBS   840832    // mbsum[64] -> pad 840960
#define OFF_XTB   840960    // X^T bf16 hi/lo [256][35][2 planes][23n][64c]

// split-bf16 helpers: x = hi + lo, each exactly representable in bf16
__device__ inline unsigned short bfh(float x) {
    unsigned u = __float_as_uint(x);
    return (unsigned short)((u + 0x7FFFu + ((u >> 16) & 1u)) >> 16);  // RNE
}
__device__ inline float bfh2f(unsigned short h) {
    return __uint_as_float(((unsigned)h) << 16);
}
// RNE f32->bf16 via HW cvt (numerically identical to bfh for finite inputs)
__device__ inline unsigned short bf16rn(float x) {
    __hip_bfloat16 h = __float2bfloat16(x);
    return __builtin_bit_cast(unsigned short, h);
}

// ---------------------------------------------------------------------------
// Kernel 0: transpose x[b][c][n][l] -> X^T bf16 hi/lo [b][l][p][n][c].
__global__ __launch_bounds__(1024) void k_xt(const float* __restrict__ x,
                                             float* __restrict__ ws) {
    int b = blockIdx.x, t = threadIdx.x;
    __shared__ float sx[64 * 23 * 18];   // 106 KB
    const float* xb = x + b * CNL;
    unsigned short* xo = (unsigned short*)(ws + OFF_XTB) + (size_t)b * NL * 2944;
    for (int lh = 0; lh < 2; lh++) {
        int l0 = lh * 18, Lc = lh ? 17 : 18;
        if (lh) __syncthreads();
        for (int i = t; i < 1472 * Lc; i += 1024) {
            int cn = i / Lc, li = i - cn * Lc;        // cn = c*23+n
            sx[cn * 18 + li] = xb[cn * 35 + l0 + li];
        }
        __syncthreads();
        for (int item = t; item < 184 * Lc; item += 1024) {
            int li = item / 184, rem = item - li * 184;
            int n = rem >> 3, k = rem & 7;
            us8 hi, lo;
            #pragma unroll
            for (int e = 0; e < 8; e++) {
                float v = sx[((8 * k + e) * 23 + n) * 18 + li];
                unsigned short hb = bfh(v);
                hi[e] = hb;
                lo[e] = bfh(v - bfh2f(hb));
            }
            unsigned short* dst = xo + (size_t)(l0 + li) * 2944 + n * 64 + 8 * k;
            *(us8*)(dst) = hi;           // plane hi
            *(us8*)(dst + 1472) = lo;    // plane lo
        }
    }
}

// ---------------------------------------------------------------------------
// Kernel 1: fold projection weights; block 3 converts mw to bf16 hi/lo + mb sum.
__global__ __launch_bounds__(256) void k_prep(const float* __restrict__ cw1,
                                              const float* __restrict__ cb1,
                                              const float* __restrict__ cw2,
                                              const float* __restrict__ cb2,
                                              const float* __restrict__ mw,
                                              const float* __restrict__ mb,
                                              float* __restrict__ ws) {
    int h = blockIdx.x, t = threadIdx.x;
    __shared__ float s1[4096], s2[4096];
    if (h < 3) {
        for (int i = t; i < 4096; i += 256) {
            s1[i] = cw1[h * 4096 + i];
            s2[i] = cw2[h * 4096 + i];
        }
        __syncthreads();
        for (int i = t; i < 4096; i += 256) {
            int c2 = i >> 6, c1 = i & 63;
            float acc = 0.f;
            for (int o = 0; o < 64; o++) acc += s2[o * 64 + c2] * s1[o * 64 + c1];
            ws[OFF_W + h * 4096 + i] = acc;
        }
        if (t < 64) {
            float a = 0.f, b2 = 0.f;
            for (int o = 0; o < 64; o++) {
                a  += cb2[h * 64 + o] * s1[o * 64 + t];
                b2 += cb1[h * 64 + o] * s2[o * 64 + t];
            }
            ws[OFF_U1 + h * 64 + t] = a;
            ws[OFF_U2 + h * 64 + t] = b2;
        }
        if (t == 0) {
            float a = 0.f;
            for (int o = 0; o < 64; o++) a += cb1[h * 64 + o] * cb2[h * 64 + o];
            ws[OFF_S + h] = a;
        }
    } else {
        unsigned short* mh = (unsigned short*)(ws + OFF_MWH);
        unsigned short* ml = (unsigned short*)(ws + OFF_MWL);
        for (int i = t; i < 12288; i += 256) {
            float v = mw[i];                 // layout [h][o][c]
            unsigned short hb = bfh(v);
            mh[i] = hb;
            ml[i] = bfh(v - bfh2f(hb));
        }
        if (t < 64) ws[OFF_MBS + t] = mb[t] + mb[64 + t] + mb[128 + t];
    }
}

// ---------------------------------------------------------------------------
// Kernel 2 (MFMA): att_m[b,h,m,n] = (sum_l X_l^T W X_l + a1[n] + a2[m] + 35*s)/2240
// T14: issue l+1 loads right after bar1; write idle buffer after phase A.
__global__ __launch_bounds__(256) void k_attm(float* __restrict__ ws) {
    const int b = blockIdx.x, h = blockIdx.y, t = threadIdx.x;
    const int lane = t & 63;
    const int w = __builtin_amdgcn_readfirstlane(t >> 6);   // wave 0..3
    const int lg = lane >> 4;      // k-group 0..3
    const int lr = lane & 15;      // row/col within 16-tile

    __shared__ unsigned short sXh[2][32 * 72];   // X^T hi, double-buffered
    __shared__ unsigned short sXl[2][32 * 72];   // X^T lo
    __shared__ unsigned short sPh[32 * 72];      // P^T hi  [n][c2]
    __shared__ unsigned short sPl[32 * 72];      // P^T lo
    __shared__ float sxs[64 * 25];               // sum_l X  [c][n], stride 25
    __shared__ float sA1[23], sA2[23];

    const unsigned short* xthl = (const unsigned short*)(ws + OFF_XTB);

    // --- W fragments (phase-A A-operand), hoisted: rows 16w+lr, split hi/lo ---
    bf16x8 wh[2], wl[2];
    {
        const float* Wg = ws + OFF_W + h * 4096 + (16 * w + lr) * 64;
        #pragma unroll
        for (int s = 0; s < 2; s++) {
            const float* p = Wg + 32 * s + 8 * lg;
            float4 v0 = *(const float4*)(p);
            float4 v1 = *(const float4*)(p + 4);
            float vv[8] = {v0.x, v0.y, v0.z, v0.w, v1.x, v1.y, v1.z, v1.w};
            #pragma unroll
            for (int e = 0; e < 8; e++) {
                unsigned short hb = bfh(vv[e]);
                wh[s][e] = (short)hb;
                wl[s][e] = (short)bfh(vv[e] - bfh2f(hb));
            }
        }
    }

    // --- staging chunk decomposition (368 = 2 planes x 23 rows x 8 chunks) ---
    const int j1 = t;                              // chunk 1 (all threads)
    const int p1 = j1 / 184, r1 = j1 - p1 * 184;
    const int n1 = r1 >> 3, k1 = r1 & 7;
    unsigned short* d1 = (p1 ? sXl[0] : sXh[0]) + n1 * 72 + 8 * k1;
    const int j2 = 256 + t;                        // chunk 2 (t<112, plane lo)
    const int r2 = j2 - 184;
    const int n2 = r2 >> 3, k2 = r2 & 7;
    unsigned short* d2 = sXl[0] + n2 * 72 + 8 * k2;

    const int mt = w >> 1, nt = w & 1;             // phase-B tile
    f32x4 attC = {0.f, 0.f, 0.f, 0.f};
    float xa1[8] = {0, 0, 0, 0, 0, 0, 0, 0};
    float xa2[8] = {0, 0, 0, 0, 0, 0, 0, 0};

    // --- prologue: stage l = 0 into buffer 0 ---
    {
        const us8* g = (const us8*)(xthl + (size_t)(b * NL) * 2944);
        us8 v1 = g[j1];
        *(us8*)(d1) = v1;
        #pragma unroll
        for (int e = 0; e < 8; e++) xa1[e] += bfh2f(v1[e]);
        if (t < 112) {
            us8 v2 = g[j2];
            *(us8*)(d2) = v2;
            #pragma unroll
            for (int e = 0; e < 8; e++) xa2[e] += bfh2f(v2[e]);
        }
    }

    #pragma unroll 1
    for (int l = 0; l < NL; l++) {
        const int cur = l & 1;
        __syncthreads();   // buf[cur] ready; prev-iter consumers done

        // issue next-l loads early (latency hides under phase A)
        us8 vn1, vn2;
        if (l < NL - 1) {
            const us8* g = (const us8*)(xthl + (size_t)(b * NL + l + 1) * 2944);
            vn1 = g[j1];
            if (t < 112) vn2 = g[j2];
        }

        const unsigned short* xh = sXh[cur];
        const unsigned short* xl = sXl[cur];

        // --- phase A: P rows [16w,16w+16) x n-tiles {0,1}, K = 64 ---
        f32x4 pc[2];
        #pragma unroll
        for (int ntt = 0; ntt < 2; ntt++) {
            f32x4 c = {0.f, 0.f, 0.f, 0.f};
            #pragma unroll
            for (int s = 0; s < 2; s++) {
                int off = (ntt * 16 + lr) * 72 + 32 * s + 8 * lg;
                bf16x8 bh = *(const bf16x8*)(xh + off);
                bf16x8 bl = *(const bf16x8*)(xl + off);
                c = __builtin_amdgcn_mfma_f32_16x16x32_bf16(wh[s], bh, c, 0, 0, 0);
                c = __builtin_amdgcn_mfma_f32_16x16x32_bf16(wh[s], bl, c, 0, 0, 0);
                c = __builtin_amdgcn_mfma_f32_16x16x32_bf16(wl[s], bh, c, 0, 0, 0);
            }
            pc[ntt] = c;
        }
        #pragma unroll
        for (int ntt = 0; ntt < 2; ntt++) {
            int n = ntt * 16 + lr;
            int c2 = 16 * w + 4 * lg;
            us4 ph4, pl4;
            #pragma unroll
            for (int r = 0; r < 4; r++) {
                float v = pc[ntt][r];
                unsigned short hb = bf16rn(v);
                ph4[r] = hb;
                pl4[r] = bf16rn(v - bfh2f(hb));
            }
            *(us4*)(sPh + n * 72 + c2) = ph4;
            *(us4*)(sPl + n * 72 + c2) = pl4;
        }

        // write-late: store next-l X into the idle buffer
        if (l < NL - 1) {
            *(us8*)(d1 + (cur ^ 1) * 2304) = vn1;
            #pragma unroll
            for (int e = 0; e < 8; e++) xa1[e] += bfh2f(vn1[e]);
            if (t < 112) {
                *(us8*)(d2 + (cur ^ 1) * 2304) = vn2;
                #pragma unroll
                for (int e = 0; e < 8; e++) xa2[e] += bfh2f(vn2[e]);
            }
        }
        __syncthreads();   // P ready

        // --- phase B: att(mt,nt) += X^T @ P, K = 64 ---
        #pragma unroll
        for (int s = 0; s < 2; s++) {
            int aoff = (mt * 16 + lr) * 72 + 32 * s + 8 * lg;
            int boff = (nt * 16 + lr) * 72 + 32 * s + 8 * lg;
            bf16x8 ah = *(const bf16x8*)(xh + aoff);
            bf16x8 al = *(const bf16x8*)(xl + aoff);
            bf16x8 bh = *(const bf16x8*)(sPh + boff);
            bf16x8 bl = *(const bf16x8*)(sPl + boff);
            attC = __builtin_amdgcn_mfma_f32_16x16x32_bf16(ah, bh, attC, 0, 0, 0);
            attC = __builtin_amdgcn_mfma_f32_16x16x32_bf16(ah, bl, attC, 0, 0, 0);
            attC = __builtin_amdgcn_mfma_f32_16x16x32_bf16(al, bh, attC, 0, 0, 0);
        }
    }

    // --- rank-1 correction terms from hi+lo column sums ---
    if (t < 184) {
        #pragma unroll
        for (int e = 0; e < 8; e++) sxs[(8 * k1 + e) * 25 + n1] = xa1[e];
    }
    __syncthreads();
    if (t >= 184) {
        #pragma unroll
        for (int e = 0; e < 8; e++) sxs[(8 * k1 + e) * 25 + n1] += xa1[e];
    }
    if (t < 112) {
        #pragma unroll
        for (int e = 0; e < 8; e++) sxs[(8 * k2 + e) * 25 + n2] += xa2[e];
    }
    __syncthreads();
    if (t < 23) {
        float a = 0.f;
        const float* u = ws + OFF_U1 + h * 64;
        for (int c = 0; c < 64; c++) a += u[c] * sxs[c * 25 + t];
        sA1[t] = a;
    } else if (t >= 32 && t < 55) {
        int n = t - 32;
        float a = 0.f;
        const float* u = ws + OFF_U2 + h * 64;
        for (int c = 0; c < 64; c++) a += u[c] * sxs[c * 25 + n];
        sA2[n] = a;
    }
    __syncthreads();

    float sh = ws[OFF_S + h];
    float* o = ws + OFF_ATTM + (size_t)b * HF + h * NSQ;
    int n = nt * 16 + lr;
    if (n < 23) {
        #pragma unroll
        for (int r = 0; r < 4; r++) {
            int m = mt * 16 + 4 * lg + r;
            if (m < 23)
                o[m * 23 + n] = (attC[r] + sA1[n] + sA2[m] + 35.f * sh) * (1.f / 2240.f);
        }
    }
}

// ---------------------------------------------------------------------------
// Kernel 3: BN batch statistics; 25 blocks x (64 features x 8 batch-groups).
__global__ __launch_bounds__(512) void k_bn(float* __restrict__ ws) {
    int t = threadIdx.x;
    int fi = t & 63, bg = t >> 6;
    int f = blockIdx.x * 64 + fi;
    __shared__ float rs[8][64], rs2[8][64];
    float s = 0.f, s2 = 0.f;
    if (f < HF) {
        const float* p = ws + OFF_ATTM + f + (size_t)bg * 32 * HF;
        for (int b = 0; b < 32; b++) {
            float v = p[b * HF];
            s += v; s2 += v * v;
        }
    }
    rs[bg][fi] = s; rs2[bg][fi] = s2;
    __syncthreads();
    if (bg == 0 && f < HF) {
        float ts = 0.f, ts2 = 0.f;
        #pragma unroll
        for (int g = 0; g < 8; g++) { ts += rs[g][fi]; ts2 += rs2[g][fi]; }
        float mean = ts * (1.f / 256.f);
        float var  = ts2 * (1.f / 256.f) - mean * mean;
        ws[OFF_MEAN + f] = mean;
        ws[OFF_RSTD + f] = rsqrtf(var + 1e-5f);
    }
}

// ---------------------------------------------------------------------------
// Kernel 4: normalize, softmax over rows, A = A_ske + att + A_adp.
__global__ __launch_bounds__(256) void k_adp(const float* __restrict__ gamma,
                                             const float* __restrict__ beta,
                                             const float* __restrict__ att,
                                             const float* __restrict__ aske,
                                             float* __restrict__ ws) {
    int b = blockIdx.x, h = blockIdx.y, t = threadIdx.x;
    __shared__ float sv[529];
    const float* am   = ws + OFF_ATTM + b * HF + h * NSQ;
    const float* mean = ws + OFF_MEAN + h * NSQ;
    const float* rstd = ws + OFF_RSTD + h * NSQ;
    for (int i = t; i < 529; i += 256) {
        sv[i] = (am[i] - mean[i]) * rstd[i] * gamma[h * NSQ + i] + beta[h * NSQ + i];
    }
    __syncthreads();
    if (t < 23) {
        float mx = -1e30f;
        #pragma unroll
        for (int m = 0; m < 23; m++) mx = fmaxf(mx, sv[m * 23 + t]);
        float e[23];
        float sum = 0.f;
        #pragma unroll
        for (int m = 0; m < 23; m++) {
            float v = __expf(sv[m * 23 + t] - mx);
            e[m] = v; sum += v;
        }
        float inv = 1.f / sum;
        #pragma unroll
        for (int m = 0; m < 23; m++) sv[m * 23 + t] = e[m] * inv;
    }
    __syncthreads();
    float* o = ws + OFF_A + b * HF + h * NSQ;
    for (int i = t; i < 529; i += 256) {
        o[i] = sv[i] + aske[h * NSQ + i] + att[h * NSQ + i];
    }
}

// ---------------------------------------------------------------------------
// Kernel 5 (fused GCN + temporal FC), one block per batch b, 8 waves.
// Y = sum_h (MW[h] @ X) @ A[h]. T14 staging; sT stride 44; sY stride 38.
#define SYS 38
#define STS 44
__global__ __launch_bounds__(512, 2) void k_fused(float* __restrict__ ws,
                                                  const float* __restrict__ wseq,
                                                  const float* __restrict__ biasp,
                                                  float* __restrict__ out) {
    const int b = blockIdx.x, t = threadIdx.x;
    const int lane = t & 63;
    const int w = __builtin_amdgcn_readfirstlane(t >> 6);   // 0..7
    const int lg = lane >> 4, lr = lane & 15;
    const int nt = w >> 2, ot = w & 3;     // phase A' tile (n-tile, o-tile)
    const int ot2 = w >> 1, mt = w & 1;    // phase B' tile (o-tile, m-tile)

    __shared__ __align__(16) unsigned short sXh[32 * 72], sXl[32 * 72];
    __shared__ __align__(16) unsigned short sAT[3][2][32 * 40];  // A^T [m][n] hi/lo
    __shared__ __align__(16) unsigned short sT[3][64 * STS];     // T [o][n] hi only
    __shared__ __align__(16) unsigned short sY[1472 * SYS];      // y bf16 [p][l]
    __shared__ __align__(16) unsigned short sWTh[48 * 40], sWTl[48 * 40]; // W^T [lp][l<32]
    __shared__ float sWt[3 * 35];        // W rows l=32..34
    __shared__ float sBias[35];

    const unsigned short* xthl = (const unsigned short*)(ws + OFF_XTB);
    const float* Ab  = ws + OFF_A + (size_t)b * HF;

    // ---- one-time: zero sX rows 23..31 (they feed phase B's K-dim via T) ----
    for (int i = t; i < 9 * 72; i += 512) {
        sXh[23 * 72 + i] = 0;
        sXl[23 * 72 + i] = 0;
    }
    // ---- one-time staging (first in-loop barrier fences all of it) ----
    for (int i = t; i < 3 * 1280; i += 512) {
        int h = i / 1280, r2 = i - h * 1280, m = r2 / 40, n = r2 - m * 40;
        float v = (n < 23 && m < 23) ? Ab[h * 529 + n * 23 + m] : 0.f;
        unsigned short hb = bfh(v);
        sAT[h][0][m * 40 + n] = hb;
        sAT[h][1][m * 40 + n] = bfh(v - bfh2f(hb));
    }
    for (int i = t; i < 48 * 40; i += 512) {
        int lp = i / 40, l = i - lp * 40;
        float v = (lp < 35 && l < 32) ? wseq[l * 35 + lp] : 0.f;
        unsigned short hb = bfh(v);
        sWTh[i] = hb;
        sWTl[i] = bfh(v - bfh2f(hb));
    }
    if (t < 105) sWt[t] = wseq[(32 + t / 35) * 35 + (t % 35)];
    if (t >= 128 && t < 163) sBias[t - 128] = biasp[t - 128];

    // ---- MW fragments as phase-A' B-operand (MW^T cols o = MW rows o) ----
    const unsigned short* mwh = (const unsigned short*)(ws + OFF_MWH);
    const unsigned short* mwl = (const unsigned short*)(ws + OFF_MWL);
    bf16x8 fwh[3][2], fwl[3][2];
    #pragma unroll
    for (int h = 0; h < 3; h++)
        #pragma unroll
        for (int s = 0; s < 2; s++) {
            int off = h * 4096 + (16 * ot + lr) * 64 + 32 * s + 8 * lg;
            fwh[h][s] = *(const bf16x8*)(mwh + off);
            fwl[h][s] = *(const bf16x8*)(mwl + off);
        }
    float4 mbsv = *(const float4*)(ws + OFF_MBS + 16 * ot2 + 4 * lg);
    float mb4[4] = {mbsv.x, mbsv.y, mbsv.z, mbsv.w};

    // staging chunk decomposition (t < 368 active)
    const int p1 = t / 184, r1 = t - p1 * 184;
    const int n1 = r1 >> 3, k1 = r1 & 7;
    unsigned short* d1 = (p1 ? sXl : sXh) + n1 * 72 + 8 * k1;

    const f32x4 zf = {0.f, 0.f, 0.f, 0.f};

    // prologue: stage l = 0
    if (t < 368) {
        const us8* g = (const us8*)(xthl + (size_t)(b * NL) * 2944);
        *(us8*)d1 = g[t];
    }

    #pragma unroll 1
    for (int l = 0; l < NL; l++) {
        __syncthreads();   // sX(l) ready

        // issue next-l load early (reg-carry; written after bar2)
        us8 vn;
        if (l < NL - 1 && t < 368) {
            const us8* g = (const us8*)(xthl + (size_t)(b * NL + l + 1) * 2944);
            vn = g[t];
        }

        // ---- phase A': T^T = X^T @ MW^T per h; M=n, N=o, K=c=64 ----
        bf16x8 xh0 = *(const bf16x8*)(sXh + (16 * nt + lr) * 72 + 8 * lg);
        bf16x8 xh1 = *(const bf16x8*)(sXh + (16 * nt + lr) * 72 + 32 + 8 * lg);
        bf16x8 xl0 = *(const bf16x8*)(sXl + (16 * nt + lr) * 72 + 8 * lg);
        bf16x8 xl1 = *(const bf16x8*)(sXl + (16 * nt + lr) * 72 + 32 + 8 * lg);
        #pragma unroll
        for (int h = 0; h < 3; h++) {
            f32x4 cH = __builtin_amdgcn_mfma_f32_16x16x32_bf16(xh0, fwh[h][0], zf, 0, 0, 0);
            cH = __builtin_amdgcn_mfma_f32_16x16x32_bf16(xh1, fwh[h][1], cH, 0, 0, 0);
            f32x4 cC = __builtin_amdgcn_mfma_f32_16x16x32_bf16(xh0, fwl[h][0], zf, 0, 0, 0);
            cC = __builtin_amdgcn_mfma_f32_16x16x32_bf16(xh1, fwl[h][1], cC, 0, 0, 0);
            cC = __builtin_amdgcn_mfma_f32_16x16x32_bf16(xl0, fwh[h][0], cC, 0, 0, 0);
            cC = __builtin_amdgcn_mfma_f32_16x16x32_bf16(xl1, fwh[h][1], cC, 0, 0, 0);
            us4 t4;
            #pragma unroll
            for (int r = 0; r < 4; r++) t4[r] = bf16rn(cH[r] + cC[r]);
            *(us4*)(&sT[h][(16 * ot + lr) * STS + 16 * nt + 4 * lg]) = t4;
        }
        __syncthreads();   // T ready; all phase-A' sX reads done

        // ---- phase B': Y(ot2,mt) = sum_h T[h] @ A[h]; K = n = 32 ----
        f32x4 Yh = zf, Yc = zf;
        #pragma unroll
        for (int h = 0; h < 3; h++) {
            union { bf16x8 v; us4 q[2]; } tu;
            tu.q[0] = *(const us4*)(&sT[h][(16 * ot2 + lr) * STS + 8 * lg]);
            tu.q[1] = *(const us4*)(&sT[h][(16 * ot2 + lr) * STS + 8 * lg + 4]);
            bf16x8 ah = *(const bf16x8*)(&sAT[h][0][(16 * mt + lr) * 40 + 8 * lg]);
            bf16x8 al = *(const bf16x8*)(&sAT[h][1][(16 * mt + lr) * 40 + 8 * lg]);
            Yh = __builtin_amdgcn_mfma_f32_16x16x32_bf16(tu.v, ah, Yh, 0, 0, 0);
            Yc = __builtin_amdgcn_mfma_f32_16x16x32_bf16(tu.v, al, Yc, 0, 0, 0);
        }
        int m = 16 * mt + lr;
        if (m < 23) {
            #pragma unroll
            for (int r = 0; r < 4; r++) {
                int o = 16 * ot2 + 4 * lg + r;
                float yv = Yh[r] + Yc[r] + mb4[r];
                sY[(o * 23 + m) * SYS + l] = bf16rn(yv);
            }
        }

        // write-late: store next-l X (safe: bar2 proved all A' readers done)
        if (l < NL - 1 && t < 368) *(us8*)d1 = vn;
    }
    __syncthreads();   // sY complete

    // ---- temporal FC: 92 p-tiles x 3 lp-tiles, K=32 MFMA + tail l=32..34 ----
    #pragma unroll 1
    for (int tt = w; tt < 276; tt += 8) {
        int pt = tt / 3, lt = tt - pt * 3;
        int pA = 16 * pt + lr;
        const unsigned short* yb = sY + pA * SYS + 8 * lg;
        union { bf16x8 v; unsigned u[4]; } au;
        au.u[0] = *(const unsigned*)(yb);
        au.u[1] = *(const unsigned*)(yb + 2);
        au.u[2] = *(const unsigned*)(yb + 4);
        au.u[3] = *(const unsigned*)(yb + 6);
        bf16x8 wbh = *(const bf16x8*)(sWTh + (16 * lt + lr) * 40 + 8 * lg);
        bf16x8 wbl = *(const bf16x8*)(sWTl + (16 * lt + lr) * 40 + 8 * lg);
        f32x4 c0 = __builtin_amdgcn_mfma_f32_16x16x32_bf16(au.v, wbh, zf, 0, 0, 0);
        f32x4 c1 = __builtin_amdgcn_mfma_f32_16x16x32_bf16(au.v, wbl, zf, 0, 0, 0);
        int lpc = 16 * lt + lr;
        if (lpc < 35) {
            float wt0 = sWt[lpc], wt1 = sWt[35 + lpc], wt2 = sWt[70 + lpc];
            float bv = sBias[lpc];
            #pragma unroll
            for (int r = 0; r < 4; r++) {
                int pr = 16 * pt + 4 * lg + r;
                const unsigned short* yt = sY + pr * SYS + 32;
                unsigned t0 = *(const unsigned*)(yt);       // l=32,33
                unsigned t1 = *(const unsigned*)(yt + 2);   // l=34, pad
                float v = c0[r] + c1[r] + bv
                        + bfh2f((unsigned short)(t0 & 0xffff)) * wt0
                        + bfh2f((unsigned short)(t0 >> 16))    * wt1
                        + bfh2f((unsigned short)(t1 & 0xffff)) * wt2;
                out[((size_t)b * 1472 + pr) * 35 + lpc] = v;
            }
        }
    }
}

// ---------------------------------------------------------------------------
extern "C" void kernel_launch(void* const* d_in, const int* in_sizes, int n_in,
                              void* d_out, int out_size, void* d_ws, size_t ws_size,
                              hipStream_t stream) {
    const float* x    = (const float*)d_in[0];
    const float* cw1  = (const float*)d_in[1];
    const float* cb1  = (const float*)d_in[2];
    const float* cw2  = (const float*)d_in[3];
    const float* cb2  = (const float*)d_in[4];
    const float* gam  = (const float*)d_in[5];
    const float* bet  = (const float*)d_in[6];
    const float* mw   = (const float*)d_in[7];
    const float* mb   = (const float*)d_in[8];
    const float* att  = (const float*)d_in[9];
    const float* aske = (const float*)d_in[10];
    const float* wsq  = (const float*)d_in[11];
    const float* bias = (const float*)d_in[12];
    float* ws = (float*)d_ws;
    float* out = (float*)d_out;

    hipLaunchKernelGGL(k_prep, dim3(4),       dim3(256),  0, stream, cw1, cb1, cw2, cb2, mw, mb, ws);
    hipLaunchKernelGGL(k_xt,   dim3(256),     dim3(1024), 0, stream, x, ws);
    hipLaunchKernelGGL(k_attm, dim3(256, 3),  dim3(256),  0, stream, ws);
    hipLaunchKernelGGL(k_bn,   dim3(25),      dim3(512),  0, stream, ws);
    hipLaunchKernelGGL(k_adp,  dim3(256, 3),  dim3(256),  0, stream, gam, bet, att, aske, ws);
    hipLaunchKernelGGL(k_fused, dim3(256),    dim3(512),  0, stream, ws, wsq, bias, out);
}